// Round 5
// baseline (192.702 us; speedup 1.0000x reference)
//
#include <hip/hip_runtime.h>
#include <hip/hip_bf16.h>

#define B_ 4
#define N_ 2048
#define D_ 512
#define H_ 8
#define DH_ 64

typedef float float4_ __attribute__((ext_vector_type(4)));
typedef int int2_ __attribute__((ext_vector_type(2)));
typedef int int4_ __attribute__((ext_vector_type(4)));
typedef unsigned short ushort4_ __attribute__((ext_vector_type(4)));
typedef unsigned short ushort8_ __attribute__((ext_vector_type(8)));
typedef __bf16 bf16x8 __attribute__((ext_vector_type(8)));
typedef _Float16 half2_ __attribute__((ext_vector_type(2)));
typedef _Float16 half4_ __attribute__((ext_vector_type(4)));
typedef _Float16 half8_ __attribute__((ext_vector_type(8)));

#if __has_builtin(__builtin_amdgcn_exp2f)
#define EXP2(x) __builtin_amdgcn_exp2f(x)   // raw v_exp_f32 (2^x), no OCML fixup
#else
#define EXP2(x) exp2f(x)
#endif

__device__ __forceinline__ float b2f(unsigned short u) {
  union { unsigned int u; float f; } v; v.u = ((unsigned int)u) << 16; return v.f;
}
__device__ __forceinline__ unsigned short f2b(float f) {
  union { float f; unsigned int u; } v; v.f = f;
  unsigned int r = v.u + 0x7fffu + ((v.u >> 16) & 1u);
  return (unsigned short)(r >> 16);
}
// packed f32x2 -> f16x2 (v_cvt_pkrtz_f16_f32); builtin returns __fp16 vec -> cast
__device__ __forceinline__ half4_ pk4(float a, float b, float c, float d) {
  half2_ lo = __builtin_bit_cast(half2_, __builtin_amdgcn_cvt_pkrtz(a, b));
  half2_ hi = __builtin_bit_cast(half2_, __builtin_amdgcn_cvt_pkrtz(c, d));
  return __builtin_bit_cast(half4_,
      (int2_){__builtin_bit_cast(int, lo), __builtin_bit_cast(int, hi)});
}

// async global->LDS, 16B per lane, dest = ldsbase + lane*16 (wave-uniform base)
#define GLD16(gp, lp)                                                        \
  __builtin_amdgcn_global_load_lds(                                          \
      (const __attribute__((address_space(1))) unsigned int*)(gp),           \
      (__attribute__((address_space(3))) unsigned int*)(lp), 16, 0, 0)

// ---------------------------------------------------------------------------
// Block-local dtype probe (verified R12): header x[0..255], exp-field>=134.
// ---------------------------------------------------------------------------
__device__ __forceinline__ bool detect_fp32_local(
    const unsigned short* __restrict__ xhdr, int* cnt_sh) {
  if (threadIdx.x == 0) *cnt_sh = 0;
  __syncthreads();
  unsigned int e = (xhdr[threadIdx.x] >> 7) & 0xFFu;
  if (e >= 134u) atomicAdd(cnt_sh, 1);
  __syncthreads();
  return *cnt_sh > 16;
}

// ---------------------------------------------------------------------------
// prep_all (verified R12): x convert + both weight transposes + Wband.
// ---------------------------------------------------------------------------
__device__ __forceinline__ void transpose_conv(
    const void* __restrict__ src, unsigned short* __restrict__ dst,
    int R, int C, int bx, int by, bool ofp) {
  __shared__ unsigned short tile[32][33];
  const int c0 = bx * 32, r0 = by * 32;
  const int tx = threadIdx.x & 31, ty = threadIdx.x >> 5;
#pragma unroll
  for (int k = 0; k < 4; ++k) {
    int r = ty + k * 8;
    long idx = (long)(r0 + r) * C + c0 + tx;
    tile[r][tx] = ofp ? f2b(((const float*)src)[idx])
                      : ((const unsigned short*)src)[idx];
  }
  __syncthreads();
#pragma unroll
  for (int k = 0; k < 4; ++k) {
    int c = ty + k * 8;
    dst[(long)(c0 + c) * R + r0 + tx] = tile[tx][c];
  }
}

__global__ __launch_bounds__(256) void prep_all(
    const void* __restrict__ xraw, const void* __restrict__ Wqraw,
    const void* __restrict__ Woraw, unsigned short* __restrict__ xb,
    unsigned short* __restrict__ WqT, unsigned short* __restrict__ WoT,
    unsigned short* __restrict__ Wband) {
  __shared__ int cnt_sh;
  const bool ofp = detect_fp32_local((const unsigned short*)xraw, &cnt_sh);
  const int bid = blockIdx.x;
  if (bid < 4096) {                       // x convert: 1048576 ushort4 units
    int i4 = bid * 256 + threadIdx.x;
    ushort4_ o;
    if (ofp) {
      float4_ v = ((const float4_*)xraw)[i4];
      o[0] = f2b(v[0]); o[1] = f2b(v[1]); o[2] = f2b(v[2]); o[3] = f2b(v[3]);
    } else {
      o = ((const ushort4_*)xraw)[i4];
    }
    *(ushort4_*)(xb + (long)i4 * 4) = o;
  } else if (bid < 5120) {
    const int b2 = bid - 4096;
    transpose_conv(Wqraw, WqT, 512, 2048, b2 % 64, b2 / 64, ofp);
  } else if (bid < 5632) {
    const int b2 = bid - 5120;
    transpose_conv(Woraw, WoT, 1024, 512, b2 % 16, b2 / 16, ofp);
  } else {
    constexpr float INV_E = 0.36787944117144233f;
    constexpr float R1 = 0.69220062755534635f;
    constexpr float INV_1MR = 3.2488706f;
    const int i = bid - 5632;
    const int krel = threadIdx.x;
    const int j = (i >> 6) * 64 - 96 + krel;
    float c = 0.f;
    if (j >= 0 && j < N_) {
      float wgt = __expf(-fabsf((float)(i - j)) * INV_E);
      float rj = __expf(-(float)j * INV_E);
      float rnj = __expf(-(float)(N_ - 1 - j) * INV_E);
      float S = 1.f + R1 * (2.f - rj - rnj) * INV_1MR;
      c = wgt / S;
    }
    _Float16 hv = (_Float16)c;
    Wband[i * 256 + krel] = __builtin_bit_cast(unsigned short, hv);
  }
}

#define MFMA16x32(d, a, b) \
  d = __builtin_amdgcn_mfma_f32_16x16x32_bf16(a, b, d, 0, 0, 0)

// ---------------------------------------------------------------------------
// gemm128p (R4): qkvt = xb @ WqT^T via the R3-verified gemm_o structure at
// 128x128 / BK=64 / 8 waves.  Grid 64x16 = 1024 blocks -> 2 resident
// blocks/CU (__launch_bounds__(512,4), LDS 64 KB) so one block's MFMAs hide
// the other's tile-end vmcnt drains.  Replaces the 256-block gemm256 which
// ran at 1 block/CU with fully-exposed per-tile drains.
// ---------------------------------------------------------------------------
__global__ __launch_bounds__(512, 4) void gemm128p(
    const unsigned short* __restrict__ A, const unsigned short* __restrict__ Bt,
    unsigned short* __restrict__ C, int M, int N, int K) {
  __shared__ unsigned short As[2][8192];    // [buf][128 rows][64 k], 16 KB plane
  __shared__ unsigned short Bs[2][8192];
  const int tid = threadIdx.x;
  const int w = tid >> 6, lane = tid & 63, l16 = lane & 15, quad = lane >> 4;
  const int wm = w >> 2, wn = w & 3;        // 2M x 4N, per-wave 64x32
  const long tm = (long)blockIdx.x * 128, tn = (long)blockIdx.y * 128;
  const int srow = tid >> 3;                // 0..63
  const int sch = (tid & 7) ^ (srow & 7);
  const unsigned short* gA = A + (tm + srow) * (long)K + sch * 8;
  const unsigned short* gB = Bt + (tn + srow) * (long)K + sch * 8;
  const int xr8 = l16 & 7;
  const int ch0 = ((0 + quad) ^ xr8) * 8;
  const int ch1 = ((4 + quad) ^ xr8) * 8;
  const int rowA0 = (wm * 64 + l16) * 64;
  const int rowB0 = (wn * 32 + l16) * 64;
  float4_ acc[4][2] = {};

  auto stage = [&](int t, int bufn) __attribute__((always_inline)) {
#pragma unroll
    for (int r = 0; r < 2; ++r)
      GLD16(gA + (long)(r * 64) * K + t * 64, &As[bufn][r * 4096 + w * 512]);
#pragma unroll
    for (int r = 0; r < 2; ++r)
      GLD16(gB + (long)(r * 64) * K + t * 64, &Bs[bufn][r * 4096 + w * 512]);
  };

  stage(0, 0);
  asm volatile("s_waitcnt vmcnt(0)" ::: "memory");
  __builtin_amdgcn_s_barrier();

  const int NT = K >> 6;
  for (int t = 0; t < NT; ++t) {
    const int buf = t & 1;
    const unsigned short* as = As[buf];
    const unsigned short* bs = Bs[buf];
    bf16x8 af[8], bf0[2], bf1[2];
#pragma unroll
    for (int mi = 0; mi < 4; ++mi) {
      af[mi * 2]     = __builtin_bit_cast(bf16x8, *(const int4_*)&as[rowA0 + mi * 1024 + ch0]);
      af[mi * 2 + 1] = __builtin_bit_cast(bf16x8, *(const int4_*)&as[rowA0 + mi * 1024 + ch1]);
    }
    bf0[0] = __builtin_bit_cast(bf16x8, *(const int4_*)&bs[rowB0 + ch0]);
    bf0[1] = __builtin_bit_cast(bf16x8, *(const int4_*)&bs[rowB0 + ch1]);
    if (t + 1 < NT) stage(t + 1, buf ^ 1);
    __builtin_amdgcn_s_barrier();
    asm volatile("s_waitcnt lgkmcnt(0)" ::: "memory");
    __builtin_amdgcn_sched_barrier(0);
    __builtin_amdgcn_s_setprio(1);
#pragma unroll
    for (int mi = 0; mi < 4; ++mi) {
      MFMA16x32(acc[mi][0], af[mi * 2], bf0[0]);
      MFMA16x32(acc[mi][0], af[mi * 2 + 1], bf0[1]);
    }
    __builtin_amdgcn_s_setprio(0);
    __builtin_amdgcn_s_barrier();
    bf1[0] = __builtin_bit_cast(bf16x8, *(const int4_*)&bs[rowB0 + 1024 + ch0]);
    bf1[1] = __builtin_bit_cast(bf16x8, *(const int4_*)&bs[rowB0 + 1024 + ch1]);
    __builtin_amdgcn_s_barrier();
    asm volatile("s_waitcnt lgkmcnt(0)" ::: "memory");
    __builtin_amdgcn_sched_barrier(0);
    __builtin_amdgcn_s_setprio(1);
#pragma unroll
    for (int mi = 0; mi < 4; ++mi) {
      MFMA16x32(acc[mi][1], af[mi * 2], bf1[0]);
      MFMA16x32(acc[mi][1], af[mi * 2 + 1], bf1[1]);
    }
    __builtin_amdgcn_s_setprio(0);
    asm volatile("s_waitcnt vmcnt(0)" ::: "memory");
    __builtin_amdgcn_sched_barrier(0);
    __builtin_amdgcn_s_barrier();
  }
#pragma unroll
  for (int nb = 0; nb < 2; ++nb) {
    long col = tn + wn * 32 + nb * 16 + l16;
#pragma unroll
    for (int mb = 0; mb < 4; ++mb)
#pragma unroll
      for (int r = 0; r < 4; ++r) {
        long row = tm + wm * 64 + mb * 16 + quad * 4 + r;
        C[row * N + col] = f2b(acc[mb][nb][r]);
      }
  }
}

// ---------------------------------------------------------------------------
// gemm_o (verified R4): output GEMM d_out = catb @ WoT^T + bias, 128x128 /
// BK=64, 8 waves, grid 64x4 = 256 blocks.
// ---------------------------------------------------------------------------
__global__ __launch_bounds__(512, 2) void gemm_o(
    const unsigned short* __restrict__ A, const unsigned short* __restrict__ Bt,
    void* __restrict__ C, const void* __restrict__ bias_raw,
    const unsigned short* __restrict__ xhdr) {
  __shared__ int cnt_sh;
  const bool ofp = detect_fp32_local(xhdr, &cnt_sh);
  __shared__ unsigned short As[2][8192];    // [buf][128 rows][64 k], 16 KB plane
  __shared__ unsigned short Bs[2][8192];
  constexpr int K = 1024, N = 512;
  const int tid = threadIdx.x;
  const int w = tid >> 6, lane = tid & 63, l16 = lane & 15, quad = lane >> 4;
  const int wm = w >> 2, wn = w & 3;        // 2M x 4N
  const long tm = (long)blockIdx.x * 128, tn = (long)blockIdx.y * 128;
  const int srow = tid >> 3;                // 0..63
  const int sch = (tid & 7) ^ (srow & 7);
  const unsigned short* gA = A + (tm + srow) * (long)K + sch * 8;
  const unsigned short* gB = Bt + (tn + srow) * (long)K + sch * 8;
  const int xr8 = l16 & 7;
  const int ch0 = ((0 + quad) ^ xr8) * 8;
  const int ch1 = ((4 + quad) ^ xr8) * 8;
  const int rowA0 = (wm * 64 + l16) * 64;
  const int rowB0 = (wn * 32 + l16) * 64;
  float4_ acc[4][2] = {};

  auto stage = [&](int t, int bufn) __attribute__((always_inline)) {
#pragma unroll
    for (int r = 0; r < 2; ++r)
      GLD16(gA + (long)(r * 64) * K + t * 64, &As[bufn][r * 4096 + w * 512]);
#pragma unroll
    for (int r = 0; r < 2; ++r)
      GLD16(gB + (long)(r * 64) * K + t * 64, &Bs[bufn][r * 4096 + w * 512]);
  };

  stage(0, 0);
  asm volatile("s_waitcnt vmcnt(0)" ::: "memory");
  __builtin_amdgcn_s_barrier();

  const int NT = K >> 6;                    // 16 K-tiles
  for (int t = 0; t < NT; ++t) {
    const int buf = t & 1;
    const unsigned short* as = As[buf];
    const unsigned short* bs = Bs[buf];
    bf16x8 af[8], bf0[2], bf1[2];
#pragma unroll
    for (int mi = 0; mi < 4; ++mi) {
      af[mi * 2]     = __builtin_bit_cast(bf16x8, *(const int4_*)&as[rowA0 + mi * 1024 + ch0]);
      af[mi * 2 + 1] = __builtin_bit_cast(bf16x8, *(const int4_*)&as[rowA0 + mi * 1024 + ch1]);
    }
    bf0[0] = __builtin_bit_cast(bf16x8, *(const int4_*)&bs[rowB0 + ch0]);
    bf0[1] = __builtin_bit_cast(bf16x8, *(const int4_*)&bs[rowB0 + ch1]);
    if (t + 1 < NT) stage(t + 1, buf ^ 1);
    __builtin_amdgcn_s_barrier();
    asm volatile("s_waitcnt lgkmcnt(0)" ::: "memory");
    __builtin_amdgcn_sched_barrier(0);
    __builtin_amdgcn_s_setprio(1);
#pragma unroll
    for (int mi = 0; mi < 4; ++mi) {
      MFMA16x32(acc[mi][0], af[mi * 2], bf0[0]);
      MFMA16x32(acc[mi][0], af[mi * 2 + 1], bf0[1]);
    }
    __builtin_amdgcn_s_setprio(0);
    __builtin_amdgcn_s_barrier();
    bf1[0] = __builtin_bit_cast(bf16x8, *(const int4_*)&bs[rowB0 + 1024 + ch0]);
    bf1[1] = __builtin_bit_cast(bf16x8, *(const int4_*)&bs[rowB0 + 1024 + ch1]);
    __builtin_amdgcn_s_barrier();
    asm volatile("s_waitcnt lgkmcnt(0)" ::: "memory");
    __builtin_amdgcn_sched_barrier(0);
    __builtin_amdgcn_s_setprio(1);
#pragma unroll
    for (int mi = 0; mi < 4; ++mi) {
      MFMA16x32(acc[mi][1], af[mi * 2], bf1[0]);
      MFMA16x32(acc[mi][1], af[mi * 2 + 1], bf1[1]);
    }
    __builtin_amdgcn_s_setprio(0);
    asm volatile("s_waitcnt vmcnt(0)" ::: "memory");
    __builtin_amdgcn_sched_barrier(0);
    __builtin_amdgcn_s_barrier();
  }
#pragma unroll
  for (int nb = 0; nb < 2; ++nb) {
    long col = tn + wn * 32 + nb * 16 + l16;
    float bv = ofp ? ((const float*)bias_raw)[col]
                   : b2f(((const unsigned short*)bias_raw)[col]);
#pragma unroll
    for (int mb = 0; mb < 4; ++mb)
#pragma unroll
      for (int r = 0; r < 4; ++r) {
        long row = tm + wm * 64 + mb * 16 + quad * 4 + r;
        float val = acc[mb][nb][r] + bv;
        if (ofp) ((float*)C)[row * N + col] = val;
        else ((unsigned short*)C)[row * N + col] = f2b(val);
      }
  }
}

// ---------------------------------------------------------------------------
// mid_all v2 (verified R2) — vectorized 16B/lane global I/O on both paths.
// ---------------------------------------------------------------------------
#define TSW 266
__global__ __launch_bounds__(256) void mid_all(
    const unsigned short* __restrict__ qkvt, unsigned short* __restrict__ Vt,
    const unsigned short* __restrict__ Wband, unsigned short* __restrict__ catb) {
  __shared__ __align__(16) unsigned short Ts[64 * TSW];  // 34 KB, aliased below
  const int bid = blockIdx.x;
  const int tid = threadIdx.x;
  if (bid < 512) {
    // ---- Vt tile: bh = bid>>4, j0 = (bid&15)*128 ----
    unsigned int* Td = (unsigned int*)Ts;           // [64 d][68 dwords]
    const int bh = bid >> 4, b = bh >> 3, h = bh & 7;
    const int j0 = (bid & 15) * 128;
    const int dg = tid & 7;
#pragma unroll
    for (int it = 0; it < 2; ++it) {
      const int jp = (tid >> 3) + 32 * it;          // j-pair index 0..63
      const long base =
          (long)(b * N_ + j0 + 2 * jp) * 2048 + 1024 + h * 64 + dg * 8;
      ushort8_ r0 = __builtin_bit_cast(ushort8_, *(const int4_*)&qkvt[base]);
      ushort8_ r1 = __builtin_bit_cast(ushort8_, *(const int4_*)&qkvt[base + 2048]);
#pragma unroll
      for (int e = 0; e < 8; ++e) {
        const int d = dg * 8 + e;
        const int S = (d >> 3) | ((d & 1) << 3);
        unsigned short h0 = __builtin_bit_cast(unsigned short, (_Float16)b2f(r0[e]));
        unsigned short h1 = __builtin_bit_cast(unsigned short, (_Float16)b2f(r1[e]));
        Td[d * 68 + (jp ^ (S << 2))] = (unsigned int)h0 | ((unsigned int)h1 << 16);
      }
    }
    __syncthreads();
#pragma unroll
    for (int it = 0; it < 4; ++it) {
      const int d = (tid >> 4) + 16 * it;           // 0..63
      const int ch = tid & 15;                      // logical 4-dword chunk
      const int S = (d >> 3) | ((d & 1) << 3);
      int4_ v = *(const int4_*)&Td[d * 68 + ((ch ^ S) << 2)];
      *(int4_*)&Vt[((long)bh * 64 + d) * 2048 + j0 + ch * 8] = v;
    }
    return;
  }
  // ---- branch2, self-staged (vectorized) ----
  const int b2 = bid - 512;
  const int qtile = b2 & 31;
  const int bh = b2 >> 5, b = bh >> 3, h = bh & 7;
  const int jlo = qtile * 64 - 96;
  {
    unsigned int* Tsd = (unsigned int*)Ts;          // dword view, row stride 133
    const int dg = tid & 7;
#pragma unroll
    for (int it = 0; it < 4; ++it) {
      const int kkp = (tid >> 3) + 32 * it;         // kk-pair 0..127
      const int jA = jlo + 2 * kkp, jB = jA + 1;
      int4_ r0 = {}, r1 = {};
      if (jA >= 0 && jA < N_)
        r0 = *(const int4_*)&qkvt[(long)(b * N_ + jA) * 2048 + 1536 + h * 64 + dg * 8];
      if (jB >= 0 && jB < N_)
        r1 = *(const int4_*)&qkvt[(long)(b * N_ + jB) * 2048 + 1536 + h * 64 + dg * 8];
      ushort8_ u0 = __builtin_bit_cast(ushort8_, r0);
      ushort8_ u1 = __builtin_bit_cast(ushort8_, r1);
#pragma unroll
      for (int e = 0; e < 8; ++e) {
        const int d = dg * 8 + e;
        unsigned short h0 = __builtin_bit_cast(unsigned short, (_Float16)b2f(u0[e]));
        unsigned short h1 = __builtin_bit_cast(unsigned short, (_Float16)b2f(u1[e]));
        Tsd[d * 133 + kkp] = (unsigned int)h0 | ((unsigned int)h1 << 16);
      }
    }
  }
  __syncthreads();
  const int w = tid >> 6, lane = tid & 63, l16 = lane & 15, quad = lane >> 4;
  const int i_row = qtile * 64 + w * 16 + l16;
  const unsigned short* ap = Wband + i_row * 256;
  float4_ acc[4] = {};
#pragma unroll
  for (int kh = 0; kh < 8; ++kh) {
    half8_ af = __builtin_bit_cast(half8_, *(const int4_*)&ap[kh * 32 + quad * 8]);
#pragma unroll
    for (int nb = 0; nb < 4; ++nb) {
      half8_ bf = __builtin_bit_cast(half8_,
          *(const int4_*)&Ts[(nb * 16 + l16) * TSW + kh * 32 + quad * 8]);
      acc[nb] = __builtin_amdgcn_mfma_f32_16x16x32_f16(af, bf, acc[nb], 0, 0, 0);
    }
  }
#pragma unroll
  for (int nb = 0; nb < 4; ++nb)
#pragma unroll
    for (int r = 0; r < 4; ++r) {
      int row = qtile * 64 + w * 16 + quad * 4 + r;
      catb[(long)(b * N_ + row) * 1024 + h * 128 + 64 + nb * 16 + l16] =
          f2b(acc[nb][r]);
    }
}

// ---------------------------------------------------------------------------
// Flash attention v10 = v9 + T5 setprio around QK and PV MFMA clusters.
// R4 evidence: time invariant to LDS traffic (R3), HBM (R4), occupancy
// (v7 vs v8) -> per-wave dependency-bound; setprio lets MFMA-entering waves
// preempt softmax-VALU waves on the same SIMD (m191: +4-7% attn).
// ---------------------------------------------------------------------------
__global__ __launch_bounds__(256) void flash_kernel(
    const unsigned short* __restrict__ qkvt, const unsigned short* __restrict__ Vt,
    unsigned short* __restrict__ catb) {
  __shared__ unsigned short Ks[2][64 * 64];  // [buf][key][dim] bf16, swizzled
  __shared__ unsigned short Vs[2][64 * 64];  // [buf][d][key] f16, swizzled
  const int flat = blockIdx.x + blockIdx.y * 16;   // 512 blocks
  const int slot = flat & 7, idx = flat >> 3;      // slot = XCD (round-robin)
  const int bh = slot * 4 + (idx >> 4);            // 4 (b,h) groups per XCD
  const int i0 = (idx & 15) * 128;
  const int b = bh >> 3, h = bh & 7;
  const int tid = threadIdx.x;
  const int w = tid >> 6, lane = tid & 63, l16 = lane & 15, quad = lane >> 4;
  const int srow8 = lane >> 3, sch = lane & 7;
  const int chK = sch ^ srow8;
  bf16x8 qf[2][2];                            // [qset][kh]
  {
    constexpr float SCL = 0.125f * 1.44269504088896f;
#pragma unroll
    for (int s2 = 0; s2 < 2; ++s2) {
      const long qrow =
          (long)(b * N_ + i0 + w * 32 + s2 * 16 + l16) * 2048 + h * 64;
#pragma unroll
      for (int kh = 0; kh < 2; ++kh) {
        ushort8_ raw = __builtin_bit_cast(ushort8_,
            *(const int4_*)&qkvt[qrow + kh * 32 + quad * 8]);
        ushort8_ sc;
#pragma unroll
        for (int e = 0; e < 8; ++e) sc[e] = f2b(b2f(raw[e]) * SCL);
        qf[s2][kh] = __builtin_bit_cast(bf16x8, sc);
      }
    }
  }
  const unsigned short* kp[2];
#pragma unroll
  for (int kh = 0; kh < 2; ++kh)
    kp[kh] = &Ks[0][l16 * 64 + (((kh * 4 + quad) ^ (l16 & 7)) * 8)];
  const unsigned short* vp[4];
#pragma unroll
  for (int c = 0; c < 4; ++c)
    vp[c] = &Vs[0][l16 * 64 + (((c * 2 + (quad >> 1)) ^ (l16 & 7)) * 8) +
                   (quad & 1) * 4];
  const unsigned short* kg[2];
  const unsigned short* vg[2];
#pragma unroll
  for (int g = 0; g < 2; ++g) {
    const int row = w * 16 + g * 8 + srow8;
    kg[g] = qkvt + (long)(b * N_ + row) * 2048 + 512 + h * 64 + chK * 8;
    vg[g] = Vt + ((long)bh * 64 + row) * 2048 + chK * 8;
  }
  float4_ O[2][4] = {};
  float4_ O5[2] = {};
  const half4_ ones = {(_Float16)1.f, (_Float16)1.f, (_Float16)1.f, (_Float16)1.f};

  auto stage = [&](int jt_, int buf_) __attribute__((always_inline)) {
    const int j0 = jt_ * 64;
#pragma unroll
    for (int g = 0; g < 2; ++g) {
      GLD16(kg[g] + (long)j0 * 2048,
            (char*)&Ks[0][0] + buf_ * 8192 + (w * 16 + g * 8) * 128);
      GLD16(vg[g] + j0,
            (char*)&Vs[0][0] + buf_ * 8192 + (w * 16 + g * 8) * 128);
    }
  };
  auto phase = [&](int jt_, int buf_) __attribute__((always_inline)) {
    if (jt_ + 1 < 32) stage(jt_ + 1, buf_ ^ 1);
    float4_ s[2][4] = {};
    __builtin_amdgcn_s_setprio(1);
#pragma unroll
    for (int kh = 0; kh < 2; ++kh)
#pragma unroll
      for (int c = 0; c < 4; ++c) {
        bf16x8 kf = __builtin_bit_cast(bf16x8,
            *(const int4_*)(kp[kh] + buf_ * 4096 + c * 1024));
#pragma unroll
        for (int s2 = 0; s2 < 2; ++s2)
          s[s2][c] = __builtin_amdgcn_mfma_f32_16x16x32_bf16(
              kf, qf[s2][kh], s[s2][c], 0, 0, 0);
      }
    __builtin_amdgcn_s_setprio(0);
    half4_ pf[2][4];
#pragma unroll
    for (int s2 = 0; s2 < 2; ++s2)
#pragma unroll
      for (int c = 0; c < 4; ++c)
        pf[s2][c] = pk4(EXP2(s[s2][c][0]), EXP2(s[s2][c][1]),
                        EXP2(s[s2][c][2]), EXP2(s[s2][c][3]));
    __builtin_amdgcn_s_setprio(1);
#pragma unroll
    for (int c = 0; c < 4; ++c) {
#pragma unroll
      for (int dblk = 0; dblk < 4; ++dblk) {
        half4_ vfv = *(const half4_*)(vp[c] + buf_ * 4096 + dblk * 1024);
#pragma unroll
        for (int s2 = 0; s2 < 2; ++s2)
          O[s2][dblk] = __builtin_amdgcn_mfma_f32_16x16x16f16(
              pf[s2][c], vfv, O[s2][dblk], 0, 0, 0);
      }
#pragma unroll
      for (int s2 = 0; s2 < 2; ++s2)
        O5[s2] = __builtin_amdgcn_mfma_f32_16x16x16f16(
            pf[s2][c], ones, O5[s2], 0, 0, 0);
    }
    __builtin_amdgcn_s_setprio(0);
    __syncthreads();
  };

  stage(0, 0);
  __syncthreads();
  for (int jt = 0; jt < 32; jt += 2) {
    phase(jt, 0);
    phase(jt + 1, 1);
  }
#pragma unroll
  for (int s2 = 0; s2 < 2; ++s2) {
    float linv[4];
#pragma unroll
    for (int r = 0; r < 4; ++r) linv[r] = 1.f / O5[s2][r];
#pragma unroll
    for (int dblk = 0; dblk < 4; ++dblk)
#pragma unroll
      for (int r = 0; r < 4; ++r) {
        int row = i0 + w * 32 + s2 * 16 + quad * 4 + r;
        catb[(long)(b * N_ + row) * 1024 + h * 128 + dblk * 16 + l16] =
            f2b(O[s2][dblk][r] * linv[r]);
      }
  }
}

// ---------------------------------------------------------------------------
extern "C" void kernel_launch(void* const* d_in, const int* in_sizes, int n_in,
                              void* d_out, int out_size, void* d_ws, size_t ws_size,
                              hipStream_t stream) {
  char* ws = (char*)d_ws;
  unsigned short* qkvt = (unsigned short*)(ws);                            // 32 MB
  unsigned short* WqT  = (unsigned short*)(ws + (size_t)32 * 1024 * 1024); //  2 MB
  unsigned short* WoT  = (unsigned short*)(ws + (size_t)34 * 1024 * 1024); //  1 MB
  unsigned short* Vt   = (unsigned short*)(ws + (size_t)35 * 1024 * 1024); //  8 MB
  unsigned short* catb = (unsigned short*)(ws + (size_t)43 * 1024 * 1024); // 16 MB
  unsigned short* xb   = (unsigned short*)(ws + (size_t)59 * 1024 * 1024); //  8 MB
  unsigned short* Wband= (unsigned short*)(ws + (size_t)68 * 1024 * 1024); //  1 MB

  prep_all<<<7680, 256, 0, stream>>>(d_in[0], d_in[1], d_in[2],
                                     xb, WqT, WoT, Wband);
  gemm128p<<<dim3(8192 / 128, 2048 / 128), 512, 0, stream>>>(
      xb, WqT, qkvt, 8192, 2048, 512);
  mid_all<<<1536, 256, 0, stream>>>(qkvt, Vt, Wband, catb);
  flash_kernel<<<dim3(2048 / 128, 32), 256, 0, stream>>>(qkvt, Vt, catb);
  gemm_o<<<dim3(8192 / 128, 512 / 128), 512, 0, stream>>>(
      catb, WoT, d_out, d_in[3], (const unsigned short*)d_in[0]);
}

// Round 6
// 183.463 us; speedup vs baseline: 1.0504x; 1.0504x over previous
//
#include <hip/hip_runtime.h>
#include <hip/hip_bf16.h>

#define B_ 4
#define N_ 2048
#define D_ 512
#define H_ 8
#define DH_ 64

typedef float float4_ __attribute__((ext_vector_type(4)));
typedef int int2_ __attribute__((ext_vector_type(2)));
typedef int int4_ __attribute__((ext_vector_type(4)));
typedef unsigned short ushort4_ __attribute__((ext_vector_type(4)));
typedef unsigned short ushort8_ __attribute__((ext_vector_type(8)));
typedef __bf16 bf16x8 __attribute__((ext_vector_type(8)));
typedef _Float16 half2_ __attribute__((ext_vector_type(2)));
typedef _Float16 half4_ __attribute__((ext_vector_type(4)));
typedef _Float16 half8_ __attribute__((ext_vector_type(8)));

#if __has_builtin(__builtin_amdgcn_exp2f)
#define EXP2(x) __builtin_amdgcn_exp2f(x)   // raw v_exp_f32 (2^x), no OCML fixup
#else
#define EXP2(x) exp2f(x)
#endif

__device__ __forceinline__ float b2f(unsigned short u) {
  union { unsigned int u; float f; } v; v.u = ((unsigned int)u) << 16; return v.f;
}
__device__ __forceinline__ unsigned short f2b(float f) {
  union { float f; unsigned int u; } v; v.f = f;
  unsigned int r = v.u + 0x7fffu + ((v.u >> 16) & 1u);
  return (unsigned short)(r >> 16);
}
// packed f32x2 -> f16x2 (v_cvt_pkrtz_f16_f32); builtin returns __fp16 vec -> cast
__device__ __forceinline__ half4_ pk4(float a, float b, float c, float d) {
  half2_ lo = __builtin_bit_cast(half2_, __builtin_amdgcn_cvt_pkrtz(a, b));
  half2_ hi = __builtin_bit_cast(half2_, __builtin_amdgcn_cvt_pkrtz(c, d));
  return __builtin_bit_cast(half4_,
      (int2_){__builtin_bit_cast(int, lo), __builtin_bit_cast(int, hi)});
}

// async global->LDS, 16B per lane, dest = ldsbase + lane*16 (wave-uniform base)
#define GLD16(gp, lp)                                                        \
  __builtin_amdgcn_global_load_lds(                                          \
      (const __attribute__((address_space(1))) unsigned int*)(gp),           \
      (__attribute__((address_space(3))) unsigned int*)(lp), 16, 0, 0)

// ---------------------------------------------------------------------------
// Block-local dtype probe (verified R12): header x[0..255], exp-field>=134.
// ---------------------------------------------------------------------------
__device__ __forceinline__ bool detect_fp32_local(
    const unsigned short* __restrict__ xhdr, int* cnt_sh) {
  if (threadIdx.x == 0) *cnt_sh = 0;
  __syncthreads();
  unsigned int e = (xhdr[threadIdx.x] >> 7) & 0xFFu;
  if (e >= 134u) atomicAdd(cnt_sh, 1);
  __syncthreads();
  return *cnt_sh > 16;
}

// ---------------------------------------------------------------------------
// prep_all (verified R12): x convert + both weight transposes + Wband.
// ---------------------------------------------------------------------------
__device__ __forceinline__ void transpose_conv(
    const void* __restrict__ src, unsigned short* __restrict__ dst,
    int R, int C, int bx, int by, bool ofp) {
  __shared__ unsigned short tile[32][33];
  const int c0 = bx * 32, r0 = by * 32;
  const int tx = threadIdx.x & 31, ty = threadIdx.x >> 5;
#pragma unroll
  for (int k = 0; k < 4; ++k) {
    int r = ty + k * 8;
    long idx = (long)(r0 + r) * C + c0 + tx;
    tile[r][tx] = ofp ? f2b(((const float*)src)[idx])
                      : ((const unsigned short*)src)[idx];
  }
  __syncthreads();
#pragma unroll
  for (int k = 0; k < 4; ++k) {
    int c = ty + k * 8;
    dst[(long)(c0 + c) * R + r0 + tx] = tile[tx][c];
  }
}

__global__ __launch_bounds__(256) void prep_all(
    const void* __restrict__ xraw, const void* __restrict__ Wqraw,
    const void* __restrict__ Woraw, unsigned short* __restrict__ xb,
    unsigned short* __restrict__ WqT, unsigned short* __restrict__ WoT,
    unsigned short* __restrict__ Wband) {
  __shared__ int cnt_sh;
  const bool ofp = detect_fp32_local((const unsigned short*)xraw, &cnt_sh);
  const int bid = blockIdx.x;
  if (bid < 4096) {                       // x convert: 1048576 ushort4 units
    int i4 = bid * 256 + threadIdx.x;
    ushort4_ o;
    if (ofp) {
      float4_ v = ((const float4_*)xraw)[i4];
      o[0] = f2b(v[0]); o[1] = f2b(v[1]); o[2] = f2b(v[2]); o[3] = f2b(v[3]);
    } else {
      o = ((const ushort4_*)xraw)[i4];
    }
    *(ushort4_*)(xb + (long)i4 * 4) = o;
  } else if (bid < 5120) {
    const int b2 = bid - 4096;
    transpose_conv(Wqraw, WqT, 512, 2048, b2 % 64, b2 / 64, ofp);
  } else if (bid < 5632) {
    const int b2 = bid - 5120;
    transpose_conv(Woraw, WoT, 1024, 512, b2 % 16, b2 / 16, ofp);
  } else {
    constexpr float INV_E = 0.36787944117144233f;
    constexpr float R1 = 0.69220062755534635f;
    constexpr float INV_1MR = 3.2488706f;
    const int i = bid - 5632;
    const int krel = threadIdx.x;
    const int j = (i >> 6) * 64 - 96 + krel;
    float c = 0.f;
    if (j >= 0 && j < N_) {
      float wgt = __expf(-fabsf((float)(i - j)) * INV_E);
      float rj = __expf(-(float)j * INV_E);
      float rnj = __expf(-(float)(N_ - 1 - j) * INV_E);
      float S = 1.f + R1 * (2.f - rj - rnj) * INV_1MR;
      c = wgt / S;
    }
    _Float16 hv = (_Float16)c;
    Wband[i * 256 + krel] = __builtin_bit_cast(unsigned short, hv);
  }
}

// ---------------------------------------------------------------------------
// 256x256 8-phase GEMM (verified R1-R4; R5 showed it beats the 128-tile
// variant by ~5 us — 256 blocks / 1 per CU is FINE at this tile size).
// qkvt = xb @ WqT^T.  512 threads = 8 waves (2M x 4N), BK=64.
// ---------------------------------------------------------------------------
#define MFMA16x32(d, a, b) \
  d = __builtin_amdgcn_mfma_f32_16x16x32_bf16(a, b, d, 0, 0, 0)

__global__ __launch_bounds__(512, 2) void gemm256(
    const unsigned short* __restrict__ A, const unsigned short* __restrict__ Bt,
    unsigned short* __restrict__ C, int M, int N, int K) {
  __shared__ unsigned short As[2][16384];   // [buf][256 rows][64 k] bf16, 64 KB
  __shared__ unsigned short Bs[2][16384];   // [buf][256 n-rows][64 k]   64 KB
  const int tid = threadIdx.x;
  const int w = tid >> 6, lane = tid & 63, l16 = lane & 15, quad = lane >> 4;
  const int wm = w >> 2, wn = w & 3;        // wave grid 2M x 4N
  const long tm = (long)blockIdx.x * 256, tn = (long)blockIdx.y * 256;

  const int srow = tid >> 3;
  const int sch = (tid & 7) ^ (srow & 7);
  const unsigned short* gA = A + (tm + srow) * (long)K + sch * 8;
  const unsigned short* gB = Bt + (tn + srow) * (long)K + sch * 8;

  const int xr8 = l16 & 7;
  const int ch0 = ((0 + quad) ^ xr8) * 8;   // ks=0 chunk
  const int ch1 = ((4 + quad) ^ xr8) * 8;   // ks=1 chunk
  const int rowA0 = (wm * 128 + l16) * 64;
  const int rowB0 = (wn * 64 + l16) * 64;

  float4_ acc[8][4] = {};

  auto stage = [&](int t, int bufn) __attribute__((always_inline)) {
#pragma unroll
    for (int r = 0; r < 4; ++r)
      GLD16(gA + (long)(r * 64) * K + t * 64, &As[bufn][r * 4096 + w * 512]);
#pragma unroll
    for (int r = 0; r < 4; ++r)
      GLD16(gB + (long)(r * 64) * K + t * 64, &Bs[bufn][r * 4096 + w * 512]);
  };

  stage(0, 0);
  asm volatile("s_waitcnt vmcnt(0)" ::: "memory");
  __builtin_amdgcn_s_barrier();

  const int NT = K >> 6;                    // 8 K-tiles of 64
  for (int t = 0; t < NT; ++t) {
    const int buf = t & 1;
    const unsigned short* as = As[buf];
    const unsigned short* bs = Bs[buf];
    bf16x8 af[8], bq[4], br[4];
    // ---- q0: A-frags m0-3 + B-frags n0-1; issue next tile's stage ----
#pragma unroll
    for (int mi = 0; mi < 4; ++mi) {
      af[mi * 2]     = __builtin_bit_cast(bf16x8, *(const int4_*)&as[rowA0 + mi * 1024 + ch0]);
      af[mi * 2 + 1] = __builtin_bit_cast(bf16x8, *(const int4_*)&as[rowA0 + mi * 1024 + ch1]);
    }
#pragma unroll
    for (int ni = 0; ni < 2; ++ni) {
      bq[ni * 2]     = __builtin_bit_cast(bf16x8, *(const int4_*)&bs[rowB0 + ni * 1024 + ch0]);
      bq[ni * 2 + 1] = __builtin_bit_cast(bf16x8, *(const int4_*)&bs[rowB0 + ni * 1024 + ch1]);
    }
    if (t + 1 < NT) stage(t + 1, buf ^ 1);
    __builtin_amdgcn_s_barrier();
    asm volatile("s_waitcnt lgkmcnt(0)" ::: "memory");
    __builtin_amdgcn_sched_barrier(0);
    __builtin_amdgcn_s_setprio(1);
#pragma unroll
    for (int mi = 0; mi < 4; ++mi)
#pragma unroll
      for (int ni = 0; ni < 2; ++ni) {
        MFMA16x32(acc[mi][ni], af[mi * 2], bq[ni * 2]);
        MFMA16x32(acc[mi][ni], af[mi * 2 + 1], bq[ni * 2 + 1]);
      }
    __builtin_amdgcn_s_setprio(0);
    __builtin_amdgcn_s_barrier();
    // ---- q1: B-frags n2-3 (A m0-3 reused) ----
#pragma unroll
    for (int ni = 0; ni < 2; ++ni) {
      br[ni * 2]     = __builtin_bit_cast(bf16x8, *(const int4_*)&bs[rowB0 + (2 + ni) * 1024 + ch0]);
      br[ni * 2 + 1] = __builtin_bit_cast(bf16x8, *(const int4_*)&bs[rowB0 + (2 + ni) * 1024 + ch1]);
    }
    __builtin_amdgcn_s_barrier();
    asm volatile("s_waitcnt lgkmcnt(0)" ::: "memory");
    __builtin_amdgcn_sched_barrier(0);
    __builtin_amdgcn_s_setprio(1);
#pragma unroll
    for (int mi = 0; mi < 4; ++mi)
#pragma unroll
      for (int ni = 0; ni < 2; ++ni) {
        MFMA16x32(acc[mi][2 + ni], af[mi * 2], br[ni * 2]);
        MFMA16x32(acc[mi][2 + ni], af[mi * 2 + 1], br[ni * 2 + 1]);
      }
    __builtin_amdgcn_s_setprio(0);
    __builtin_amdgcn_s_barrier();
    // ---- q2: A-frags m4-7 (B n2-3 reused) ----
#pragma unroll
    for (int mi = 0; mi < 4; ++mi) {
      af[mi * 2]     = __builtin_bit_cast(bf16x8, *(const int4_*)&as[rowA0 + (4 + mi) * 1024 + ch0]);
      af[mi * 2 + 1] = __builtin_bit_cast(bf16x8, *(const int4_*)&as[rowA0 + (4 + mi) * 1024 + ch1]);
    }
    __builtin_amdgcn_s_barrier();
    asm volatile("s_waitcnt lgkmcnt(0)" ::: "memory");
    __builtin_amdgcn_sched_barrier(0);
    __builtin_amdgcn_s_setprio(1);
#pragma unroll
    for (int mi = 0; mi < 4; ++mi)
#pragma unroll
      for (int ni = 0; ni < 2; ++ni) {
        MFMA16x32(acc[4 + mi][2 + ni], af[mi * 2], br[ni * 2]);
        MFMA16x32(acc[4 + mi][2 + ni], af[mi * 2 + 1], br[ni * 2 + 1]);
      }
    __builtin_amdgcn_s_setprio(0);
    __builtin_amdgcn_s_barrier();
    // ---- q3: B-frags n0-1 again; end-of-tile vmcnt drain ----
#pragma unroll
    for (int ni = 0; ni < 2; ++ni) {
      bq[ni * 2]     = __builtin_bit_cast(bf16x8, *(const int4_*)&bs[rowB0 + ni * 1024 + ch0]);
      bq[ni * 2 + 1] = __builtin_bit_cast(bf16x8, *(const int4_*)&bs[rowB0 + ni * 1024 + ch1]);
    }
    __builtin_amdgcn_s_barrier();
    asm volatile("s_waitcnt lgkmcnt(0)" ::: "memory");
    __builtin_amdgcn_sched_barrier(0);
    __builtin_amdgcn_s_setprio(1);
#pragma unroll
    for (int mi = 0; mi < 4; ++mi)
#pragma unroll
      for (int ni = 0; ni < 2; ++ni) {
        MFMA16x32(acc[4 + mi][ni], af[mi * 2], bq[ni * 2]);
        MFMA16x32(acc[4 + mi][ni], af[mi * 2 + 1], bq[ni * 2 + 1]);
      }
    __builtin_amdgcn_s_setprio(0);
    asm volatile("s_waitcnt vmcnt(0)" ::: "memory");
    __builtin_amdgcn_sched_barrier(0);
    __builtin_amdgcn_s_barrier();
  }
#pragma unroll
  for (int ni = 0; ni < 4; ++ni) {
    long col = tn + wn * 64 + ni * 16 + l16;
#pragma unroll
    for (int mi = 0; mi < 8; ++mi)
#pragma unroll
      for (int r = 0; r < 4; ++r) {
        long row = tm + wm * 128 + mi * 16 + quad * 4 + r;
        C[row * N + col] = f2b(acc[mi][ni][r]);
      }
  }
}

// ---------------------------------------------------------------------------
// gemm_o (verified R4): output GEMM d_out = catb @ WoT^T + bias, 128x128 /
// BK=64, 8 waves, grid 64x4 = 256 blocks.
// ---------------------------------------------------------------------------
__global__ __launch_bounds__(512, 2) void gemm_o(
    const unsigned short* __restrict__ A, const unsigned short* __restrict__ Bt,
    void* __restrict__ C, const void* __restrict__ bias_raw,
    const unsigned short* __restrict__ xhdr) {
  __shared__ int cnt_sh;
  const bool ofp = detect_fp32_local(xhdr, &cnt_sh);
  __shared__ unsigned short As[2][8192];    // [buf][128 rows][64 k], 16 KB plane
  __shared__ unsigned short Bs[2][8192];
  constexpr int K = 1024, N = 512;
  const int tid = threadIdx.x;
  const int w = tid >> 6, lane = tid & 63, l16 = lane & 15, quad = lane >> 4;
  const int wm = w >> 2, wn = w & 3;        // 2M x 4N
  const long tm = (long)blockIdx.x * 128, tn = (long)blockIdx.y * 128;
  const int srow = tid >> 3;                // 0..63
  const int sch = (tid & 7) ^ (srow & 7);
  const unsigned short* gA = A + (tm + srow) * (long)K + sch * 8;
  const unsigned short* gB = Bt + (tn + srow) * (long)K + sch * 8;
  const int xr8 = l16 & 7;
  const int ch0 = ((0 + quad) ^ xr8) * 8;
  const int ch1 = ((4 + quad) ^ xr8) * 8;
  const int rowA0 = (wm * 64 + l16) * 64;
  const int rowB0 = (wn * 32 + l16) * 64;
  float4_ acc[4][2] = {};

  auto stage = [&](int t, int bufn) __attribute__((always_inline)) {
#pragma unroll
    for (int r = 0; r < 2; ++r)
      GLD16(gA + (long)(r * 64) * K + t * 64, &As[bufn][r * 4096 + w * 512]);
#pragma unroll
    for (int r = 0; r < 2; ++r)
      GLD16(gB + (long)(r * 64) * K + t * 64, &Bs[bufn][r * 4096 + w * 512]);
  };

  stage(0, 0);
  asm volatile("s_waitcnt vmcnt(0)" ::: "memory");
  __builtin_amdgcn_s_barrier();

  const int NT = K >> 6;                    // 16 K-tiles
  for (int t = 0; t < NT; ++t) {
    const int buf = t & 1;
    const unsigned short* as = As[buf];
    const unsigned short* bs = Bs[buf];
    bf16x8 af[8], bf0[2], bf1[2];
#pragma unroll
    for (int mi = 0; mi < 4; ++mi) {
      af[mi * 2]     = __builtin_bit_cast(bf16x8, *(const int4_*)&as[rowA0 + mi * 1024 + ch0]);
      af[mi * 2 + 1] = __builtin_bit_cast(bf16x8, *(const int4_*)&as[rowA0 + mi * 1024 + ch1]);
    }
    bf0[0] = __builtin_bit_cast(bf16x8, *(const int4_*)&bs[rowB0 + ch0]);
    bf0[1] = __builtin_bit_cast(bf16x8, *(const int4_*)&bs[rowB0 + ch1]);
    if (t + 1 < NT) stage(t + 1, buf ^ 1);
    __builtin_amdgcn_s_barrier();
    asm volatile("s_waitcnt lgkmcnt(0)" ::: "memory");
    __builtin_amdgcn_sched_barrier(0);
    __builtin_amdgcn_s_setprio(1);
#pragma unroll
    for (int mi = 0; mi < 4; ++mi) {
      MFMA16x32(acc[mi][0], af[mi * 2], bf0[0]);
      MFMA16x32(acc[mi][0], af[mi * 2 + 1], bf0[1]);
    }
    __builtin_amdgcn_s_setprio(0);
    __builtin_amdgcn_s_barrier();
    bf1[0] = __builtin_bit_cast(bf16x8, *(const int4_*)&bs[rowB0 + 1024 + ch0]);
    bf1[1] = __builtin_bit_cast(bf16x8, *(const int4_*)&bs[rowB0 + 1024 + ch1]);
    __builtin_amdgcn_s_barrier();
    asm volatile("s_waitcnt lgkmcnt(0)" ::: "memory");
    __builtin_amdgcn_sched_barrier(0);
    __builtin_amdgcn_s_setprio(1);
#pragma unroll
    for (int mi = 0; mi < 4; ++mi) {
      MFMA16x32(acc[mi][1], af[mi * 2], bf1[0]);
      MFMA16x32(acc[mi][1], af[mi * 2 + 1], bf1[1]);
    }
    __builtin_amdgcn_s_setprio(0);
    asm volatile("s_waitcnt vmcnt(0)" ::: "memory");
    __builtin_amdgcn_sched_barrier(0);
    __builtin_amdgcn_s_barrier();
  }
#pragma unroll
  for (int nb = 0; nb < 2; ++nb) {
    long col = tn + wn * 32 + nb * 16 + l16;
    float bv = ofp ? ((const float*)bias_raw)[col]
                   : b2f(((const unsigned short*)bias_raw)[col]);
#pragma unroll
    for (int mb = 0; mb < 4; ++mb)
#pragma unroll
      for (int r = 0; r < 4; ++r) {
        long row = tm + wm * 64 + mb * 16 + quad * 4 + r;
        float val = acc[mb][nb][r] + bv;
        if (ofp) ((float*)C)[row * N + col] = val;
        else ((unsigned short*)C)[row * N + col] = f2b(val);
      }
  }
}

// ---------------------------------------------------------------------------
// mid_all v2 (verified R2) — vectorized 16B/lane global I/O on both paths.
// ---------------------------------------------------------------------------
#define TSW 266
__global__ __launch_bounds__(256) void mid_all(
    const unsigned short* __restrict__ qkvt, unsigned short* __restrict__ Vt,
    const unsigned short* __restrict__ Wband, unsigned short* __restrict__ catb) {
  __shared__ __align__(16) unsigned short Ts[64 * TSW];  // 34 KB, aliased below
  const int bid = blockIdx.x;
  const int tid = threadIdx.x;
  if (bid < 512) {
    // ---- Vt tile: bh = bid>>4, j0 = (bid&15)*128 ----
    unsigned int* Td = (unsigned int*)Ts;           // [64 d][68 dwords]
    const int bh = bid >> 4, b = bh >> 3, h = bh & 7;
    const int j0 = (bid & 15) * 128;
    const int dg = tid & 7;
#pragma unroll
    for (int it = 0; it < 2; ++it) {
      const int jp = (tid >> 3) + 32 * it;          // j-pair index 0..63
      const long base =
          (long)(b * N_ + j0 + 2 * jp) * 2048 + 1024 + h * 64 + dg * 8;
      ushort8_ r0 = __builtin_bit_cast(ushort8_, *(const int4_*)&qkvt[base]);
      ushort8_ r1 = __builtin_bit_cast(ushort8_, *(const int4_*)&qkvt[base + 2048]);
#pragma unroll
      for (int e = 0; e < 8; ++e) {
        const int d = dg * 8 + e;
        const int S = (d >> 3) | ((d & 1) << 3);
        unsigned short h0 = __builtin_bit_cast(unsigned short, (_Float16)b2f(r0[e]));
        unsigned short h1 = __builtin_bit_cast(unsigned short, (_Float16)b2f(r1[e]));
        Td[d * 68 + (jp ^ (S << 2))] = (unsigned int)h0 | ((unsigned int)h1 << 16);
      }
    }
    __syncthreads();
#pragma unroll
    for (int it = 0; it < 4; ++it) {
      const int d = (tid >> 4) + 16 * it;           // 0..63
      const int ch = tid & 15;                      // logical 4-dword chunk
      const int S = (d >> 3) | ((d & 1) << 3);
      int4_ v = *(const int4_*)&Td[d * 68 + ((ch ^ S) << 2)];
      *(int4_*)&Vt[((long)bh * 64 + d) * 2048 + j0 + ch * 8] = v;
    }
    return;
  }
  // ---- branch2, self-staged (vectorized) ----
  const int b2 = bid - 512;
  const int qtile = b2 & 31;
  const int bh = b2 >> 5, b = bh >> 3, h = bh & 7;
  const int jlo = qtile * 64 - 96;
  {
    unsigned int* Tsd = (unsigned int*)Ts;          // dword view, row stride 133
    const int dg = tid & 7;
#pragma unroll
    for (int it = 0; it < 4; ++it) {
      const int kkp = (tid >> 3) + 32 * it;         // kk-pair 0..127
      const int jA = jlo + 2 * kkp, jB = jA + 1;
      int4_ r0 = {}, r1 = {};
      if (jA >= 0 && jA < N_)
        r0 = *(const int4_*)&qkvt[(long)(b * N_ + jA) * 2048 + 1536 + h * 64 + dg * 8];
      if (jB >= 0 && jB < N_)
        r1 = *(const int4_*)&qkvt[(long)(b * N_ + jB) * 2048 + 1536 + h * 64 + dg * 8];
      ushort8_ u0 = __builtin_bit_cast(ushort8_, r0);
      ushort8_ u1 = __builtin_bit_cast(ushort8_, r1);
#pragma unroll
      for (int e = 0; e < 8; ++e) {
        const int d = dg * 8 + e;
        unsigned short h0 = __builtin_bit_cast(unsigned short, (_Float16)b2f(u0[e]));
        unsigned short h1 = __builtin_bit_cast(unsigned short, (_Float16)b2f(u1[e]));
        Tsd[d * 133 + kkp] = (unsigned int)h0 | ((unsigned int)h1 << 16);
      }
    }
  }
  __syncthreads();
  const int w = tid >> 6, lane = tid & 63, l16 = lane & 15, quad = lane >> 4;
  const int i_row = qtile * 64 + w * 16 + l16;
  const unsigned short* ap = Wband + i_row * 256;
  float4_ acc[4] = {};
#pragma unroll
  for (int kh = 0; kh < 8; ++kh) {
    half8_ af = __builtin_bit_cast(half8_, *(const int4_*)&ap[kh * 32 + quad * 8]);
#pragma unroll
    for (int nb = 0; nb < 4; ++nb) {
      half8_ bf = __builtin_bit_cast(half8_,
          *(const int4_*)&Ts[(nb * 16 + l16) * TSW + kh * 32 + quad * 8]);
      acc[nb] = __builtin_amdgcn_mfma_f32_16x16x32_f16(af, bf, acc[nb], 0, 0, 0);
    }
  }
#pragma unroll
  for (int nb = 0; nb < 4; ++nb)
#pragma unroll
    for (int r = 0; r < 4; ++r) {
      int row = qtile * 64 + w * 16 + quad * 4 + r;
      catb[(long)(b * N_ + row) * 1024 + h * 128 + 64 + nb * 16 + l16] =
          f2b(acc[nb][r]);
    }
}

// ---------------------------------------------------------------------------
// Flash attention v11 = v9 (XCD remap, no setprio) + T15 PV-deferral.
// R5 evidence: time invariant to LDS/HBM/occupancy/setprio; MfmaUtil 40% +
// VALUBusy 41% = serialized pipes.  Restructure: phase i does QK(i), then
// PV(i-1) (independent of QK(i) and of exp(i)), then exp(i)->pf_cur.  The
// compiler can now interleave exp VALU into the 56-MFMA QK+PV cluster's
// pipe-busy slots.  V staging runs one phase behind K staging so 2 LDS
// buffers still suffice (V(i) staged in phase i, read as PV(i) in phase i+1).
// Summation order unchanged -> numerically identical.
// ---------------------------------------------------------------------------
__global__ __launch_bounds__(256) void flash_kernel(
    const unsigned short* __restrict__ qkvt, const unsigned short* __restrict__ Vt,
    unsigned short* __restrict__ catb) {
  __shared__ unsigned short Ks[2][64 * 64];  // [buf][key][dim] bf16, swizzled
  __shared__ unsigned short Vs[2][64 * 64];  // [buf][d][key] f16, swizzled
  const int flat = blockIdx.x + blockIdx.y * 16;   // 512 blocks
  const int slot = flat & 7, idx = flat >> 3;      // slot = XCD (round-robin)
  const int bh = slot * 4 + (idx >> 4);            // 4 (b,h) groups per XCD
  const int i0 = (idx & 15) * 128;
  const int b = bh >> 3, h = bh & 7;
  const int tid = threadIdx.x;
  const int w = tid >> 6, lane = tid & 63, l16 = lane & 15, quad = lane >> 4;
  const int srow8 = lane >> 3, sch = lane & 7;
  const int chK = sch ^ srow8;
  bf16x8 qf[2][2];                            // [qset][kh]
  {
    constexpr float SCL = 0.125f * 1.44269504088896f;
#pragma unroll
    for (int s2 = 0; s2 < 2; ++s2) {
      const long qrow =
          (long)(b * N_ + i0 + w * 32 + s2 * 16 + l16) * 2048 + h * 64;
#pragma unroll
      for (int kh = 0; kh < 2; ++kh) {
        ushort8_ raw = __builtin_bit_cast(ushort8_,
            *(const int4_*)&qkvt[qrow + kh * 32 + quad * 8]);
        ushort8_ sc;
#pragma unroll
        for (int e = 0; e < 8; ++e) sc[e] = f2b(b2f(raw[e]) * SCL);
        qf[s2][kh] = __builtin_bit_cast(bf16x8, sc);
      }
    }
  }
  const unsigned short* kp[2];
#pragma unroll
  for (int kh = 0; kh < 2; ++kh)
    kp[kh] = &Ks[0][l16 * 64 + (((kh * 4 + quad) ^ (l16 & 7)) * 8)];
  const unsigned short* vp[4];
#pragma unroll
  for (int c = 0; c < 4; ++c)
    vp[c] = &Vs[0][l16 * 64 + (((c * 2 + (quad >> 1)) ^ (l16 & 7)) * 8) +
                   (quad & 1) * 4];
  const unsigned short* kg[2];
  const unsigned short* vg[2];
#pragma unroll
  for (int g = 0; g < 2; ++g) {
    const int row = w * 16 + g * 8 + srow8;
    kg[g] = qkvt + (long)(b * N_ + row) * 2048 + 512 + h * 64 + chK * 8;
    vg[g] = Vt + ((long)bh * 64 + row) * 2048 + chK * 8;
  }
  float4_ O[2][4] = {};
  float4_ O5[2] = {};
  const half4_ ones = {(_Float16)1.f, (_Float16)1.f, (_Float16)1.f, (_Float16)1.f};

  auto stage_k = [&](int jt_, int buf_) __attribute__((always_inline)) {
    const int j0 = jt_ * 64;
#pragma unroll
    for (int g = 0; g < 2; ++g)
      GLD16(kg[g] + (long)j0 * 2048,
            (char*)&Ks[0][0] + buf_ * 8192 + (w * 16 + g * 8) * 128);
  };
  auto stage_v = [&](int jt_, int buf_) __attribute__((always_inline)) {
    const int j0 = jt_ * 64;
#pragma unroll
    for (int g = 0; g < 2; ++g)
      GLD16(vg[g] + j0,
            (char*)&Vs[0][0] + buf_ * 8192 + (w * 16 + g * 8) * 128);
  };
  // one PV accumulation step from pf (prev phase's P) against Vs buffer vb
  auto pv_step = [&](half4_ (&pf)[2][4], int vb) __attribute__((always_inline)) {
#pragma unroll
    for (int c = 0; c < 4; ++c) {
#pragma unroll
      for (int dblk = 0; dblk < 4; ++dblk) {
        half4_ vfv = *(const half4_*)(vp[c] + vb + dblk * 1024);
#pragma unroll
        for (int s2 = 0; s2 < 2; ++s2)
          O[s2][dblk] = __builtin_amdgcn_mfma_f32_16x16x16f16(
              pf[s2][c], vfv, O[s2][dblk], 0, 0, 0);
      }
#pragma unroll
      for (int s2 = 0; s2 < 2; ++s2)
        O5[s2] = __builtin_amdgcn_mfma_f32_16x16x16f16(
            pf[s2][c], ones, O5[s2], 0, 0, 0);
    }
  };
  // phase i: stage K(i+1), stage V(i), QK(i), PV(i-1) [pfp], exp(i)->pfc
  auto phase = [&](int i, half4_ (&pfp)[2][4], half4_ (&pfc)[2][4],
                   bool first, bool last) __attribute__((always_inline)) {
    if (!last) stage_k(i + 1, (i + 1) & 1);
    stage_v(i, i & 1);
    const int kb = (i & 1) * 4096;
    float4_ s[2][4] = {};
#pragma unroll
    for (int kh = 0; kh < 2; ++kh)
#pragma unroll
      for (int c = 0; c < 4; ++c) {
        bf16x8 kf = __builtin_bit_cast(bf16x8,
            *(const int4_*)(kp[kh] + kb + c * 1024));
#pragma unroll
        for (int s2 = 0; s2 < 2; ++s2)
          s[s2][c] = __builtin_amdgcn_mfma_f32_16x16x32_bf16(
              kf, qf[s2][kh], s[s2][c], 0, 0, 0);
      }
    if (!first) pv_step(pfp, ((i - 1) & 1) * 4096);
#pragma unroll
    for (int s2 = 0; s2 < 2; ++s2)
#pragma unroll
      for (int c = 0; c < 4; ++c)
        pfc[s2][c] = pk4(EXP2(s[s2][c][0]), EXP2(s[s2][c][1]),
                         EXP2(s[s2][c][2]), EXP2(s[s2][c][3]));
    __syncthreads();
  };

  half4_ pfA[2][4], pfB[2][4];
  stage_k(0, 0);
  asm volatile("s_waitcnt vmcnt(0)" ::: "memory");
  __builtin_amdgcn_s_barrier();
  phase(0, pfB, pfA, true, false);          // QK(0), exp(0)->pfA
  for (int jt = 1; jt < 31; jt += 2) {
    phase(jt, pfA, pfB, false, false);      // PV(jt-1) via pfA, exp->pfB
    phase(jt + 1, pfB, pfA, false, false);  // PV(jt)   via pfB, exp->pfA
  }
  phase(31, pfA, pfB, false, true);         // PV(30) via pfA, exp(31)->pfB
  pv_step(pfB, (31 & 1) * 4096);            // final PV(31), Vs buf 1 (drained)

#pragma unroll
  for (int s2 = 0; s2 < 2; ++s2) {
    float linv[4];
#pragma unroll
    for (int r = 0; r < 4; ++r) linv[r] = 1.f / O5[s2][r];
#pragma unroll
    for (int dblk = 0; dblk < 4; ++dblk)
#pragma unroll
      for (int r = 0; r < 4; ++r) {
        int row = i0 + w * 32 + s2 * 16 + quad * 4 + r;
        catb[(long)(b * N_ + row) * 1024 + h * 128 + dblk * 16 + l16] =
            f2b(O[s2][dblk][r] * linv[r]);
      }
  }
}

// ---------------------------------------------------------------------------
extern "C" void kernel_launch(void* const* d_in, const int* in_sizes, int n_in,
                              void* d_out, int out_size, void* d_ws, size_t ws_size,
                              hipStream_t stream) {
  char* ws = (char*)d_ws;
  unsigned short* qkvt = (unsigned short*)(ws);                            // 32 MB
  unsigned short* WqT  = (unsigned short*)(ws + (size_t)32 * 1024 * 1024); //  2 MB
  unsigned short* WoT  = (unsigned short*)(ws + (size_t)34 * 1024 * 1024); //  1 MB
  unsigned short* Vt   = (unsigned short*)(ws + (size_t)35 * 1024 * 1024); //  8 MB
  unsigned short* catb = (unsigned short*)(ws + (size_t)43 * 1024 * 1024); // 16 MB
  unsigned short* xb   = (unsigned short*)(ws + (size_t)59 * 1024 * 1024); //  8 MB
  unsigned short* Wband= (unsigned short*)(ws + (size_t)68 * 1024 * 1024); //  1 MB

  prep_all<<<7680, 256, 0, stream>>>(d_in[0], d_in[1], d_in[2],
                                     xb, WqT, WoT, Wband);
  gemm256<<<dim3(8192 / 256, 2048 / 256), 512, 0, stream>>>(
      xb, WqT, qkvt, 8192, 2048, 512);
  mid_all<<<1536, 256, 0, stream>>>(qkvt, Vt, Wband, catb);
  flash_kernel<<<dim3(2048 / 128, 32), 256, 0, stream>>>(qkvt, Vt, catb);
  gemm_o<<<dim3(8192 / 128, 512 / 128), 512, 0, stream>>>(
      catb, WoT, d_out, d_in[3], (const unsigned short*)d_in[0]);
}

// Round 7
// 182.816 us; speedup vs baseline: 1.0541x; 1.0035x over previous
//
#include <hip/hip_runtime.h>
#include <hip/hip_bf16.h>

#define B_ 4
#define N_ 2048
#define D_ 512
#define H_ 8
#define DH_ 64

typedef float float4_ __attribute__((ext_vector_type(4)));
typedef int int2_ __attribute__((ext_vector_type(2)));
typedef int int4_ __attribute__((ext_vector_type(4)));
typedef unsigned short ushort4_ __attribute__((ext_vector_type(4)));
typedef unsigned short ushort8_ __attribute__((ext_vector_type(8)));
typedef __bf16 bf16x8 __attribute__((ext_vector_type(8)));
typedef _Float16 half2_ __attribute__((ext_vector_type(2)));
typedef _Float16 half4_ __attribute__((ext_vector_type(4)));
typedef _Float16 half8_ __attribute__((ext_vector_type(8)));

#if __has_builtin(__builtin_amdgcn_exp2f)
#define EXP2(x) __builtin_amdgcn_exp2f(x)   // raw v_exp_f32 (2^x), no OCML fixup
#else
#define EXP2(x) exp2f(x)
#endif

__device__ __forceinline__ float b2f(unsigned short u) {
  union { unsigned int u; float f; } v; v.u = ((unsigned int)u) << 16; return v.f;
}
__device__ __forceinline__ unsigned short f2b(float f) {
  union { float f; unsigned int u; } v; v.f = f;
  unsigned int r = v.u + 0x7fffu + ((v.u >> 16) & 1u);
  return (unsigned short)(r >> 16);
}
// packed f32x2 -> f16x2 (v_cvt_pkrtz_f16_f32); builtin returns __fp16 vec -> cast
__device__ __forceinline__ half4_ pk4(float a, float b, float c, float d) {
  half2_ lo = __builtin_bit_cast(half2_, __builtin_amdgcn_cvt_pkrtz(a, b));
  half2_ hi = __builtin_bit_cast(half2_, __builtin_amdgcn_cvt_pkrtz(c, d));
  return __builtin_bit_cast(half4_,
      (int2_){__builtin_bit_cast(int, lo), __builtin_bit_cast(int, hi)});
}
__device__ __forceinline__ half8_ cat44(half4_ a, half4_ b) {
  int2_ ia = __builtin_bit_cast(int2_, a), ib = __builtin_bit_cast(int2_, b);
  int4_ r = {ia[0], ia[1], ib[0], ib[1]};
  return __builtin_bit_cast(half8_, r);
}

// async global->LDS, 16B per lane, dest = ldsbase + lane*16 (wave-uniform base)
#define GLD16(gp, lp)                                                        \
  __builtin_amdgcn_global_load_lds(                                          \
      (const __attribute__((address_space(1))) unsigned int*)(gp),           \
      (__attribute__((address_space(3))) unsigned int*)(lp), 16, 0, 0)

// ---------------------------------------------------------------------------
// Block-local dtype probe (verified R12): header x[0..255], exp-field>=134.
// ---------------------------------------------------------------------------
__device__ __forceinline__ bool detect_fp32_local(
    const unsigned short* __restrict__ xhdr, int* cnt_sh) {
  if (threadIdx.x == 0) *cnt_sh = 0;
  __syncthreads();
  unsigned int e = (xhdr[threadIdx.x] >> 7) & 0xFFu;
  if (e >= 134u) atomicAdd(cnt_sh, 1);
  __syncthreads();
  return *cnt_sh > 16;
}

// ---------------------------------------------------------------------------
// prep_all (verified R12): x convert + both weight transposes + Wband.
// ---------------------------------------------------------------------------
__device__ __forceinline__ void transpose_conv(
    const void* __restrict__ src, unsigned short* __restrict__ dst,
    int R, int C, int bx, int by, bool ofp) {
  __shared__ unsigned short tile[32][33];
  const int c0 = bx * 32, r0 = by * 32;
  const int tx = threadIdx.x & 31, ty = threadIdx.x >> 5;
#pragma unroll
  for (int k = 0; k < 4; ++k) {
    int r = ty + k * 8;
    long idx = (long)(r0 + r) * C + c0 + tx;
    tile[r][tx] = ofp ? f2b(((const float*)src)[idx])
                      : ((const unsigned short*)src)[idx];
  }
  __syncthreads();
#pragma unroll
  for (int k = 0; k < 4; ++k) {
    int c = ty + k * 8;
    dst[(long)(c0 + c) * R + r0 + tx] = tile[tx][c];
  }
}

__global__ __launch_bounds__(256) void prep_all(
    const void* __restrict__ xraw, const void* __restrict__ Wqraw,
    const void* __restrict__ Woraw, unsigned short* __restrict__ xb,
    unsigned short* __restrict__ WqT, unsigned short* __restrict__ WoT,
    unsigned short* __restrict__ Wband) {
  __shared__ int cnt_sh;
  const bool ofp = detect_fp32_local((const unsigned short*)xraw, &cnt_sh);
  const int bid = blockIdx.x;
  if (bid < 4096) {                       // x convert: 1048576 ushort4 units
    int i4 = bid * 256 + threadIdx.x;
    ushort4_ o;
    if (ofp) {
      float4_ v = ((const float4_*)xraw)[i4];
      o[0] = f2b(v[0]); o[1] = f2b(v[1]); o[2] = f2b(v[2]); o[3] = f2b(v[3]);
    } else {
      o = ((const ushort4_*)xraw)[i4];
    }
    *(ushort4_*)(xb + (long)i4 * 4) = o;
  } else if (bid < 5120) {
    const int b2 = bid - 4096;
    transpose_conv(Wqraw, WqT, 512, 2048, b2 % 64, b2 / 64, ofp);
  } else if (bid < 5632) {
    const int b2 = bid - 5120;
    transpose_conv(Woraw, WoT, 1024, 512, b2 % 16, b2 / 16, ofp);
  } else {
    constexpr float INV_E = 0.36787944117144233f;
    constexpr float R1 = 0.69220062755534635f;
    constexpr float INV_1MR = 3.2488706f;
    const int i = bid - 5632;
    const int krel = threadIdx.x;
    const int j = (i >> 6) * 64 - 96 + krel;
    float c = 0.f;
    if (j >= 0 && j < N_) {
      float wgt = __expf(-fabsf((float)(i - j)) * INV_E);
      float rj = __expf(-(float)j * INV_E);
      float rnj = __expf(-(float)(N_ - 1 - j) * INV_E);
      float S = 1.f + R1 * (2.f - rj - rnj) * INV_1MR;
      c = wgt / S;
    }
    _Float16 hv = (_Float16)c;
    Wband[i * 256 + krel] = __builtin_bit_cast(unsigned short, hv);
  }
}

// ---------------------------------------------------------------------------
// 256x256 8-phase GEMM (verified R1-R4; R5 showed it beats the 128-tile
// variant by ~5 us — 256 blocks / 1 per CU is FINE at this tile size).
// qkvt = xb @ WqT^T.  512 threads = 8 waves (2M x 4N), BK=64.
// ---------------------------------------------------------------------------
#define MFMA16x32(d, a, b) \
  d = __builtin_amdgcn_mfma_f32_16x16x32_bf16(a, b, d, 0, 0, 0)

__global__ __launch_bounds__(512, 2) void gemm256(
    const unsigned short* __restrict__ A, const unsigned short* __restrict__ Bt,
    unsigned short* __restrict__ C, int M, int N, int K) {
  __shared__ unsigned short As[2][16384];   // [buf][256 rows][64 k] bf16, 64 KB
  __shared__ unsigned short Bs[2][16384];   // [buf][256 n-rows][64 k]   64 KB
  const int tid = threadIdx.x;
  const int w = tid >> 6, lane = tid & 63, l16 = lane & 15, quad = lane >> 4;
  const int wm = w >> 2, wn = w & 3;        // wave grid 2M x 4N
  const long tm = (long)blockIdx.x * 256, tn = (long)blockIdx.y * 256;

  const int srow = tid >> 3;
  const int sch = (tid & 7) ^ (srow & 7);
  const unsigned short* gA = A + (tm + srow) * (long)K + sch * 8;
  const unsigned short* gB = Bt + (tn + srow) * (long)K + sch * 8;

  const int xr8 = l16 & 7;
  const int ch0 = ((0 + quad) ^ xr8) * 8;   // ks=0 chunk
  const int ch1 = ((4 + quad) ^ xr8) * 8;   // ks=1 chunk
  const int rowA0 = (wm * 128 + l16) * 64;
  const int rowB0 = (wn * 64 + l16) * 64;

  float4_ acc[8][4] = {};

  auto stage = [&](int t, int bufn) __attribute__((always_inline)) {
#pragma unroll
    for (int r = 0; r < 4; ++r)
      GLD16(gA + (long)(r * 64) * K + t * 64, &As[bufn][r * 4096 + w * 512]);
#pragma unroll
    for (int r = 0; r < 4; ++r)
      GLD16(gB + (long)(r * 64) * K + t * 64, &Bs[bufn][r * 4096 + w * 512]);
  };

  stage(0, 0);
  asm volatile("s_waitcnt vmcnt(0)" ::: "memory");
  __builtin_amdgcn_s_barrier();

  const int NT = K >> 6;                    // 8 K-tiles of 64
  for (int t = 0; t < NT; ++t) {
    const int buf = t & 1;
    const unsigned short* as = As[buf];
    const unsigned short* bs = Bs[buf];
    bf16x8 af[8], bq[4], br[4];
    // ---- q0: A-frags m0-3 + B-frags n0-1; issue next tile's stage ----
#pragma unroll
    for (int mi = 0; mi < 4; ++mi) {
      af[mi * 2]     = __builtin_bit_cast(bf16x8, *(const int4_*)&as[rowA0 + mi * 1024 + ch0]);
      af[mi * 2 + 1] = __builtin_bit_cast(bf16x8, *(const int4_*)&as[rowA0 + mi * 1024 + ch1]);
    }
#pragma unroll
    for (int ni = 0; ni < 2; ++ni) {
      bq[ni * 2]     = __builtin_bit_cast(bf16x8, *(const int4_*)&bs[rowB0 + ni * 1024 + ch0]);
      bq[ni * 2 + 1] = __builtin_bit_cast(bf16x8, *(const int4_*)&bs[rowB0 + ni * 1024 + ch1]);
    }
    if (t + 1 < NT) stage(t + 1, buf ^ 1);
    __builtin_amdgcn_s_barrier();
    asm volatile("s_waitcnt lgkmcnt(0)" ::: "memory");
    __builtin_amdgcn_sched_barrier(0);
    __builtin_amdgcn_s_setprio(1);
#pragma unroll
    for (int mi = 0; mi < 4; ++mi)
#pragma unroll
      for (int ni = 0; ni < 2; ++ni) {
        MFMA16x32(acc[mi][ni], af[mi * 2], bq[ni * 2]);
        MFMA16x32(acc[mi][ni], af[mi * 2 + 1], bq[ni * 2 + 1]);
      }
    __builtin_amdgcn_s_setprio(0);
    __builtin_amdgcn_s_barrier();
    // ---- q1: B-frags n2-3 (A m0-3 reused) ----
#pragma unroll
    for (int ni = 0; ni < 2; ++ni) {
      br[ni * 2]     = __builtin_bit_cast(bf16x8, *(const int4_*)&bs[rowB0 + (2 + ni) * 1024 + ch0]);
      br[ni * 2 + 1] = __builtin_bit_cast(bf16x8, *(const int4_*)&bs[rowB0 + (2 + ni) * 1024 + ch1]);
    }
    __builtin_amdgcn_s_barrier();
    asm volatile("s_waitcnt lgkmcnt(0)" ::: "memory");
    __builtin_amdgcn_sched_barrier(0);
    __builtin_amdgcn_s_setprio(1);
#pragma unroll
    for (int mi = 0; mi < 4; ++mi)
#pragma unroll
      for (int ni = 0; ni < 2; ++ni) {
        MFMA16x32(acc[mi][2 + ni], af[mi * 2], br[ni * 2]);
        MFMA16x32(acc[mi][2 + ni], af[mi * 2 + 1], br[ni * 2 + 1]);
      }
    __builtin_amdgcn_s_setprio(0);
    __builtin_amdgcn_s_barrier();
    // ---- q2: A-frags m4-7 (B n2-3 reused) ----
#pragma unroll
    for (int mi = 0; mi < 4; ++mi) {
      af[mi * 2]     = __builtin_bit_cast(bf16x8, *(const int4_*)&as[rowA0 + (4 + mi) * 1024 + ch0]);
      af[mi * 2 + 1] = __builtin_bit_cast(bf16x8, *(const int4_*)&as[rowA0 + (4 + mi) * 1024 + ch1]);
    }
    __builtin_amdgcn_s_barrier();
    asm volatile("s_waitcnt lgkmcnt(0)" ::: "memory");
    __builtin_amdgcn_sched_barrier(0);
    __builtin_amdgcn_s_setprio(1);
#pragma unroll
    for (int mi = 0; mi < 4; ++mi)
#pragma unroll
      for (int ni = 0; ni < 2; ++ni) {
        MFMA16x32(acc[4 + mi][2 + ni], af[mi * 2], br[ni * 2]);
        MFMA16x32(acc[4 + mi][2 + ni], af[mi * 2 + 1], br[ni * 2 + 1]);
      }
    __builtin_amdgcn_s_setprio(0);
    __builtin_amdgcn_s_barrier();
    // ---- q3: B-frags n0-1 again; end-of-tile vmcnt drain ----
#pragma unroll
    for (int ni = 0; ni < 2; ++ni) {
      bq[ni * 2]     = __builtin_bit_cast(bf16x8, *(const int4_*)&bs[rowB0 + ni * 1024 + ch0]);
      bq[ni * 2 + 1] = __builtin_bit_cast(bf16x8, *(const int4_*)&bs[rowB0 + ni * 1024 + ch1]);
    }
    __builtin_amdgcn_s_barrier();
    asm volatile("s_waitcnt lgkmcnt(0)" ::: "memory");
    __builtin_amdgcn_sched_barrier(0);
    __builtin_amdgcn_s_setprio(1);
#pragma unroll
    for (int mi = 0; mi < 4; ++mi)
#pragma unroll
      for (int ni = 0; ni < 2; ++ni) {
        MFMA16x32(acc[4 + mi][ni], af[mi * 2], bq[ni * 2]);
        MFMA16x32(acc[4 + mi][ni], af[mi * 2 + 1], bq[ni * 2 + 1]);
      }
    __builtin_amdgcn_s_setprio(0);
    asm volatile("s_waitcnt vmcnt(0)" ::: "memory");
    __builtin_amdgcn_sched_barrier(0);
    __builtin_amdgcn_s_barrier();
  }
#pragma unroll
  for (int ni = 0; ni < 4; ++ni) {
    long col = tn + wn * 64 + ni * 16 + l16;
#pragma unroll
    for (int mi = 0; mi < 8; ++mi)
#pragma unroll
      for (int r = 0; r < 4; ++r) {
        long row = tm + wm * 128 + mi * 16 + quad * 4 + r;
        C[row * N + col] = f2b(acc[mi][ni][r]);
      }
  }
}

// ---------------------------------------------------------------------------
// gemm_o (verified R4): output GEMM d_out = catb @ WoT^T + bias, 128x128 /
// BK=64, 8 waves, grid 64x4 = 256 blocks.
// ---------------------------------------------------------------------------
__global__ __launch_bounds__(512, 2) void gemm_o(
    const unsigned short* __restrict__ A, const unsigned short* __restrict__ Bt,
    void* __restrict__ C, const void* __restrict__ bias_raw,
    const unsigned short* __restrict__ xhdr) {
  __shared__ int cnt_sh;
  const bool ofp = detect_fp32_local(xhdr, &cnt_sh);
  __shared__ unsigned short As[2][8192];    // [buf][128 rows][64 k], 16 KB plane
  __shared__ unsigned short Bs[2][8192];
  constexpr int K = 1024, N = 512;
  const int tid = threadIdx.x;
  const int w = tid >> 6, lane = tid & 63, l16 = lane & 15, quad = lane >> 4;
  const int wm = w >> 2, wn = w & 3;        // 2M x 4N
  const long tm = (long)blockIdx.x * 128, tn = (long)blockIdx.y * 128;
  const int srow = tid >> 3;                // 0..63
  const int sch = (tid & 7) ^ (srow & 7);
  const unsigned short* gA = A + (tm + srow) * (long)K + sch * 8;
  const unsigned short* gB = Bt + (tn + srow) * (long)K + sch * 8;
  const int xr8 = l16 & 7;
  const int ch0 = ((0 + quad) ^ xr8) * 8;
  const int ch1 = ((4 + quad) ^ xr8) * 8;
  const int rowA0 = (wm * 64 + l16) * 64;
  const int rowB0 = (wn * 32 + l16) * 64;
  float4_ acc[4][2] = {};

  auto stage = [&](int t, int bufn) __attribute__((always_inline)) {
#pragma unroll
    for (int r = 0; r < 2; ++r)
      GLD16(gA + (long)(r * 64) * K + t * 64, &As[bufn][r * 4096 + w * 512]);
#pragma unroll
    for (int r = 0; r < 2; ++r)
      GLD16(gB + (long)(r * 64) * K + t * 64, &Bs[bufn][r * 4096 + w * 512]);
  };

  stage(0, 0);
  asm volatile("s_waitcnt vmcnt(0)" ::: "memory");
  __builtin_amdgcn_s_barrier();

  const int NT = K >> 6;                    // 16 K-tiles
  for (int t = 0; t < NT; ++t) {
    const int buf = t & 1;
    const unsigned short* as = As[buf];
    const unsigned short* bs = Bs[buf];
    bf16x8 af[8], bf0[2], bf1[2];
#pragma unroll
    for (int mi = 0; mi < 4; ++mi) {
      af[mi * 2]     = __builtin_bit_cast(bf16x8, *(const int4_*)&as[rowA0 + mi * 1024 + ch0]);
      af[mi * 2 + 1] = __builtin_bit_cast(bf16x8, *(const int4_*)&as[rowA0 + mi * 1024 + ch1]);
    }
    bf0[0] = __builtin_bit_cast(bf16x8, *(const int4_*)&bs[rowB0 + ch0]);
    bf0[1] = __builtin_bit_cast(bf16x8, *(const int4_*)&bs[rowB0 + ch1]);
    if (t + 1 < NT) stage(t + 1, buf ^ 1);
    __builtin_amdgcn_s_barrier();
    asm volatile("s_waitcnt lgkmcnt(0)" ::: "memory");
    __builtin_amdgcn_sched_barrier(0);
    __builtin_amdgcn_s_setprio(1);
#pragma unroll
    for (int mi = 0; mi < 4; ++mi) {
      MFMA16x32(acc[mi][0], af[mi * 2], bf0[0]);
      MFMA16x32(acc[mi][0], af[mi * 2 + 1], bf0[1]);
    }
    __builtin_amdgcn_s_setprio(0);
    __builtin_amdgcn_s_barrier();
    bf1[0] = __builtin_bit_cast(bf16x8, *(const int4_*)&bs[rowB0 + 1024 + ch0]);
    bf1[1] = __builtin_bit_cast(bf16x8, *(const int4_*)&bs[rowB0 + 1024 + ch1]);
    __builtin_amdgcn_s_barrier();
    asm volatile("s_waitcnt lgkmcnt(0)" ::: "memory");
    __builtin_amdgcn_sched_barrier(0);
    __builtin_amdgcn_s_setprio(1);
#pragma unroll
    for (int mi = 0; mi < 4; ++mi) {
      MFMA16x32(acc[mi][1], af[mi * 2], bf1[0]);
      MFMA16x32(acc[mi][1], af[mi * 2 + 1], bf1[1]);
    }
    __builtin_amdgcn_s_setprio(0);
    asm volatile("s_waitcnt vmcnt(0)" ::: "memory");
    __builtin_amdgcn_sched_barrier(0);
    __builtin_amdgcn_s_barrier();
  }
#pragma unroll
  for (int nb = 0; nb < 2; ++nb) {
    long col = tn + wn * 32 + nb * 16 + l16;
    float bv = ofp ? ((const float*)bias_raw)[col]
                   : b2f(((const unsigned short*)bias_raw)[col]);
#pragma unroll
    for (int mb = 0; mb < 4; ++mb)
#pragma unroll
      for (int r = 0; r < 4; ++r) {
        long row = tm + wm * 64 + mb * 16 + quad * 4 + r;
        float val = acc[mb][nb][r] + bv;
        if (ofp) ((float*)C)[row * N + col] = val;
        else ((unsigned short*)C)[row * N + col] = f2b(val);
      }
  }
}

// ---------------------------------------------------------------------------
// mid_all v2 (verified R2) — vectorized 16B/lane global I/O on both paths.
// ---------------------------------------------------------------------------
#define TSW 266
__global__ __launch_bounds__(256) void mid_all(
    const unsigned short* __restrict__ qkvt, unsigned short* __restrict__ Vt,
    const unsigned short* __restrict__ Wband, unsigned short* __restrict__ catb) {
  __shared__ __align__(16) unsigned short Ts[64 * TSW];  // 34 KB, aliased below
  const int bid = blockIdx.x;
  const int tid = threadIdx.x;
  if (bid < 512) {
    // ---- Vt tile: bh = bid>>4, j0 = (bid&15)*128 ----
    unsigned int* Td = (unsigned int*)Ts;           // [64 d][68 dwords]
    const int bh = bid >> 4, b = bh >> 3, h = bh & 7;
    const int j0 = (bid & 15) * 128;
    const int dg = tid & 7;
#pragma unroll
    for (int it = 0; it < 2; ++it) {
      const int jp = (tid >> 3) + 32 * it;          // j-pair index 0..63
      const long base =
          (long)(b * N_ + j0 + 2 * jp) * 2048 + 1024 + h * 64 + dg * 8;
      ushort8_ r0 = __builtin_bit_cast(ushort8_, *(const int4_*)&qkvt[base]);
      ushort8_ r1 = __builtin_bit_cast(ushort8_, *(const int4_*)&qkvt[base + 2048]);
#pragma unroll
      for (int e = 0; e < 8; ++e) {
        const int d = dg * 8 + e;
        const int S = (d >> 3) | ((d & 1) << 3);
        unsigned short h0 = __builtin_bit_cast(unsigned short, (_Float16)b2f(r0[e]));
        unsigned short h1 = __builtin_bit_cast(unsigned short, (_Float16)b2f(r1[e]));
        Td[d * 68 + (jp ^ (S << 2))] = (unsigned int)h0 | ((unsigned int)h1 << 16);
      }
    }
    __syncthreads();
#pragma unroll
    for (int it = 0; it < 4; ++it) {
      const int d = (tid >> 4) + 16 * it;           // 0..63
      const int ch = tid & 15;                      // logical 4-dword chunk
      const int S = (d >> 3) | ((d & 1) << 3);
      int4_ v = *(const int4_*)&Td[d * 68 + ((ch ^ S) << 2)];
      *(int4_*)&Vt[((long)bh * 64 + d) * 2048 + j0 + ch * 8] = v;
    }
    return;
  }
  // ---- branch2, self-staged (vectorized) ----
  const int b2 = bid - 512;
  const int qtile = b2 & 31;
  const int bh = b2 >> 5, b = bh >> 3, h = bh & 7;
  const int jlo = qtile * 64 - 96;
  {
    unsigned int* Tsd = (unsigned int*)Ts;          // dword view, row stride 133
    const int dg = tid & 7;
#pragma unroll
    for (int it = 0; it < 4; ++it) {
      const int kkp = (tid >> 3) + 32 * it;         // kk-pair 0..127
      const int jA = jlo + 2 * kkp, jB = jA + 1;
      int4_ r0 = {}, r1 = {};
      if (jA >= 0 && jA < N_)
        r0 = *(const int4_*)&qkvt[(long)(b * N_ + jA) * 2048 + 1536 + h * 64 + dg * 8];
      if (jB >= 0 && jB < N_)
        r1 = *(const int4_*)&qkvt[(long)(b * N_ + jB) * 2048 + 1536 + h * 64 + dg * 8];
      ushort8_ u0 = __builtin_bit_cast(ushort8_, r0);
      ushort8_ u1 = __builtin_bit_cast(ushort8_, r1);
#pragma unroll
      for (int e = 0; e < 8; ++e) {
        const int d = dg * 8 + e;
        unsigned short h0 = __builtin_bit_cast(unsigned short, (_Float16)b2f(u0[e]));
        unsigned short h1 = __builtin_bit_cast(unsigned short, (_Float16)b2f(u1[e]));
        Tsd[d * 133 + kkp] = (unsigned int)h0 | ((unsigned int)h1 << 16);
      }
    }
  }
  __syncthreads();
  const int w = tid >> 6, lane = tid & 63, l16 = lane & 15, quad = lane >> 4;
  const int i_row = qtile * 64 + w * 16 + l16;
  const unsigned short* ap = Wband + i_row * 256;
  float4_ acc[4] = {};
#pragma unroll
  for (int kh = 0; kh < 8; ++kh) {
    half8_ af = __builtin_bit_cast(half8_, *(const int4_*)&ap[kh * 32 + quad * 8]);
#pragma unroll
    for (int nb = 0; nb < 4; ++nb) {
      half8_ bf = __builtin_bit_cast(half8_,
          *(const int4_*)&Ts[(nb * 16 + l16) * TSW + kh * 32 + quad * 8]);
      acc[nb] = __builtin_amdgcn_mfma_f32_16x16x32_f16(af, bf, acc[nb], 0, 0, 0);
    }
  }
#pragma unroll
  for (int nb = 0; nb < 4; ++nb)
#pragma unroll
    for (int r = 0; r < 4; ++r) {
      int row = qtile * 64 + w * 16 + quad * 4 + r;
      catb[(long)(b * N_ + row) * 1024 + h * 128 + 64 + nb * 16 + l16] =
          f2b(acc[nb][r]);
    }
}

// ---------------------------------------------------------------------------
// Flash attention v12 = v11 (XCD remap + T15 PV-deferral) + K=32 PV.
// PV was 40x mfma_16x16x16f16/phase (half FLOP rate per MFMA slot).  Now:
// K-staging permutes token->LDS-row via T(p) = bit-shuffle so the QK D-frag
// lands in the 16x16x32 A-layout (keys quad*8..+7 per lane after concat of
// pf pairs); V B-frag is a 16B contiguous Vs read (same contiguous-quad*8
// pattern as the verified gemm256/mid_all K=32 fragments).  20 MFMA/phase
// instead of 40; V LDS reads b64x16 -> b128x8.  Softmax sums permutation-
// invariant; summation regrouping within f16 MFMA tolerance.
// ---------------------------------------------------------------------------
__global__ __launch_bounds__(256) void flash_kernel(
    const unsigned short* __restrict__ qkvt, const unsigned short* __restrict__ Vt,
    unsigned short* __restrict__ catb) {
  __shared__ unsigned short Ks[2][64 * 64];  // [buf][key][dim] bf16, swizzled
  __shared__ unsigned short Vs[2][64 * 64];  // [buf][d][key] f16, swizzled
  const int flat = blockIdx.x + blockIdx.y * 16;   // 512 blocks
  const int slot = flat & 7, idx = flat >> 3;      // slot = XCD (round-robin)
  const int bh = slot * 4 + (idx >> 4);            // 4 (b,h) groups per XCD
  const int i0 = (idx & 15) * 128;
  const int b = bh >> 3, h = bh & 7;
  const int tid = threadIdx.x;
  const int w = tid >> 6, lane = tid & 63, l16 = lane & 15, quad = lane >> 4;
  const int srow8 = lane >> 3, sch = lane & 7;
  const int chK = sch ^ srow8;
  bf16x8 qf[2][2];                            // [qset][kh]
  {
    constexpr float SCL = 0.125f * 1.44269504088896f;
#pragma unroll
    for (int s2 = 0; s2 < 2; ++s2) {
      const long qrow =
          (long)(b * N_ + i0 + w * 32 + s2 * 16 + l16) * 2048 + h * 64;
#pragma unroll
      for (int kh = 0; kh < 2; ++kh) {
        ushort8_ raw = __builtin_bit_cast(ushort8_,
            *(const int4_*)&qkvt[qrow + kh * 32 + quad * 8]);
        ushort8_ sc;
#pragma unroll
        for (int e = 0; e < 8; ++e) sc[e] = f2b(b2f(raw[e]) * SCL);
        qf[s2][kh] = __builtin_bit_cast(bf16x8, sc);
      }
    }
  }
  const unsigned short* kp[2];
#pragma unroll
  for (int kh = 0; kh < 2; ++kh)
    kp[kh] = &Ks[0][l16 * 64 + (((kh * 4 + quad) ^ (l16 & 7)) * 8)];
  // K=32 PV: window wd reads 16B = keys wd*32 + quad*8 .. +7 at d-row l16
  const unsigned short* vp32[2];
#pragma unroll
  for (int wd = 0; wd < 2; ++wd)
    vp32[wd] = &Vs[0][l16 * 64 + (((wd * 4 + quad) ^ (l16 & 7)) * 8)];
  const unsigned short* kg[2];
  const unsigned short* vg[2];
#pragma unroll
  for (int g = 0; g < 2; ++g) {
    const int prow = w * 16 + g * 8 + srow8;   // LDS row this thread stages
    // token permutation: LDS row p holds token T(p) so QK D-frag lands in
    // K=32 A-layout.  T = {p5, p3, p2, p4, p1, p0} (bijective bit shuffle).
    const int ptok = (prow & 0x20) | ((prow & 0x10) >> 2) |
                     ((prow & 0x0C) << 1) | (prow & 3);
    kg[g] = qkvt + (long)(b * N_ + ptok) * 2048 + 512 + h * 64 + chK * 8;
    vg[g] = Vt + ((long)bh * 64 + prow) * 2048 + chK * 8;   // V unpermuted
  }
  float4_ O[2][4] = {};
  float4_ O5[2] = {};
  const half8_ ones8 = {(_Float16)1.f, (_Float16)1.f, (_Float16)1.f, (_Float16)1.f,
                        (_Float16)1.f, (_Float16)1.f, (_Float16)1.f, (_Float16)1.f};

  auto stage_k = [&](int jt_, int buf_) __attribute__((always_inline)) {
    const int j0 = jt_ * 64;
#pragma unroll
    for (int g = 0; g < 2; ++g)
      GLD16(kg[g] + (long)j0 * 2048,
            (char*)&Ks[0][0] + buf_ * 8192 + (w * 16 + g * 8) * 128);
  };
  auto stage_v = [&](int jt_, int buf_) __attribute__((always_inline)) {
    const int j0 = jt_ * 64;
#pragma unroll
    for (int g = 0; g < 2; ++g)
      GLD16(vg[g] + j0,
            (char*)&Vs[0][0] + buf_ * 8192 + (w * 16 + g * 8) * 128);
  };
  // one PV accumulation step from pf (prev phase's P) against Vs buffer vb
  auto pv_step = [&](half4_ (&pf)[2][4], int vb) __attribute__((always_inline)) {
#pragma unroll
    for (int wd = 0; wd < 2; ++wd) {
      half8_ pa0 = cat44(pf[0][2 * wd], pf[0][2 * wd + 1]);
      half8_ pa1 = cat44(pf[1][2 * wd], pf[1][2 * wd + 1]);
#pragma unroll
      for (int dblk = 0; dblk < 4; ++dblk) {
        half8_ vfv = *(const half8_*)(vp32[wd] + vb + dblk * 1024);
        O[0][dblk] = __builtin_amdgcn_mfma_f32_16x16x32_f16(
            pa0, vfv, O[0][dblk], 0, 0, 0);
        O[1][dblk] = __builtin_amdgcn_mfma_f32_16x16x32_f16(
            pa1, vfv, O[1][dblk], 0, 0, 0);
      }
      O5[0] = __builtin_amdgcn_mfma_f32_16x16x32_f16(pa0, ones8, O5[0], 0, 0, 0);
      O5[1] = __builtin_amdgcn_mfma_f32_16x16x32_f16(pa1, ones8, O5[1], 0, 0, 0);
    }
  };
  // phase i: stage K(i+1), stage V(i), QK(i), PV(i-1) [pfp], exp(i)->pfc
  auto phase = [&](int i, half4_ (&pfp)[2][4], half4_ (&pfc)[2][4],
                   bool first, bool last) __attribute__((always_inline)) {
    if (!last) stage_k(i + 1, (i + 1) & 1);
    stage_v(i, i & 1);
    const int kb = (i & 1) * 4096;
    float4_ s[2][4] = {};
#pragma unroll
    for (int kh = 0; kh < 2; ++kh)
#pragma unroll
      for (int c = 0; c < 4; ++c) {
        bf16x8 kf = __builtin_bit_cast(bf16x8,
            *(const int4_*)(kp[kh] + kb + c * 1024));
#pragma unroll
        for (int s2 = 0; s2 < 2; ++s2)
          s[s2][c] = __builtin_amdgcn_mfma_f32_16x16x32_bf16(
              kf, qf[s2][kh], s[s2][c], 0, 0, 0);
      }
    if (!first) pv_step(pfp, ((i - 1) & 1) * 4096);
#pragma unroll
    for (int s2 = 0; s2 < 2; ++s2)
#pragma unroll
      for (int c = 0; c < 4; ++c)
        pfc[s2][c] = pk4(EXP2(s[s2][c][0]), EXP2(s[s2][c][1]),
                         EXP2(s[s2][c][2]), EXP2(s[s2][c][3]));
    __syncthreads();
  };

  half4_ pfA[2][4], pfB[2][4];
  stage_k(0, 0);
  asm volatile("s_waitcnt vmcnt(0)" ::: "memory");
  __builtin_amdgcn_s_barrier();
  phase(0, pfB, pfA, true, false);          // QK(0), exp(0)->pfA
  for (int jt = 1; jt < 31; jt += 2) {
    phase(jt, pfA, pfB, false, false);      // PV(jt-1) via pfA, exp->pfB
    phase(jt + 1, pfB, pfA, false, false);  // PV(jt)   via pfB, exp->pfA
  }
  phase(31, pfA, pfB, false, true);         // PV(30) via pfA, exp(31)->pfB
  pv_step(pfB, (31 & 1) * 4096);            // final PV(31), Vs buf 1 (drained)

#pragma unroll
  for (int s2 = 0; s2 < 2; ++s2) {
    float linv[4];
#pragma unroll
    for (int r = 0; r < 4; ++r) linv[r] = 1.f / O5[s2][r];
#pragma unroll
    for (int dblk = 0; dblk < 4; ++dblk)
#pragma unroll
      for (int r = 0; r < 4; ++r) {
        int row = i0 + w * 32 + s2 * 16 + quad * 4 + r;
        catb[(long)(b * N_ + row) * 1024 + h * 128 + dblk * 16 + l16] =
            f2b(O[s2][dblk][r] * linv[r]);
      }
  }
}

// ---------------------------------------------------------------------------
extern "C" void kernel_launch(void* const* d_in, const int* in_sizes, int n_in,
                              void* d_out, int out_size, void* d_ws, size_t ws_size,
                              hipStream_t stream) {
  char* ws = (char*)d_ws;
  unsigned short* qkvt = (unsigned short*)(ws);                            // 32 MB
  unsigned short* WqT  = (unsigned short*)(ws + (size_t)32 * 1024 * 1024); //  2 MB
  unsigned short* WoT  = (unsigned short*)(ws + (size_t)34 * 1024 * 1024); //  1 MB
  unsigned short* Vt   = (unsigned short*)(ws + (size_t)35 * 1024 * 1024); //  8 MB
  unsigned short* catb = (unsigned short*)(ws + (size_t)43 * 1024 * 1024); // 16 MB
  unsigned short* xb   = (unsigned short*)(ws + (size_t)59 * 1024 * 1024); //  8 MB
  unsigned short* Wband= (unsigned short*)(ws + (size_t)68 * 1024 * 1024); //  1 MB

  prep_all<<<7680, 256, 0, stream>>>(d_in[0], d_in[1], d_in[2],
                                     xb, WqT, WoT, Wband);
  gemm256<<<dim3(8192 / 256, 2048 / 256), 512, 0, stream>>>(
      xb, WqT, qkvt, 8192, 2048, 512);
  mid_all<<<1536, 256, 0, stream>>>(qkvt, Vt, Wband, catb);
  flash_kernel<<<dim3(2048 / 128, 32), 256, 0, stream>>>(qkvt, Vt, catb);
  gemm_o<<<dim3(8192 / 128, 512 / 128), 512, 0, stream>>>(
      catb, WoT, d_out, d_in[3], (const unsigned short*)d_in[0]);
}

// Round 8
// 181.699 us; speedup vs baseline: 1.0606x; 1.0061x over previous
//
#include <hip/hip_runtime.h>
#include <hip/hip_bf16.h>

#define B_ 4
#define N_ 2048
#define D_ 512
#define H_ 8
#define DH_ 64

typedef float float4_ __attribute__((ext_vector_type(4)));
typedef int int2_ __attribute__((ext_vector_type(2)));
typedef int int4_ __attribute__((ext_vector_type(4)));
typedef unsigned short ushort4_ __attribute__((ext_vector_type(4)));
typedef unsigned short ushort8_ __attribute__((ext_vector_type(8)));
typedef __bf16 bf16x8 __attribute__((ext_vector_type(8)));
typedef _Float16 half2_ __attribute__((ext_vector_type(2)));
typedef _Float16 half4_ __attribute__((ext_vector_type(4)));
typedef _Float16 half8_ __attribute__((ext_vector_type(8)));

#if __has_builtin(__builtin_amdgcn_exp2f)
#define EXP2(x) __builtin_amdgcn_exp2f(x)   // raw v_exp_f32 (2^x), no OCML fixup
#else
#define EXP2(x) exp2f(x)
#endif

__device__ __forceinline__ float b2f(unsigned short u) {
  union { unsigned int u; float f; } v; v.u = ((unsigned int)u) << 16; return v.f;
}
__device__ __forceinline__ unsigned short f2b(float f) {
  union { float f; unsigned int u; } v; v.f = f;
  unsigned int r = v.u + 0x7fffu + ((v.u >> 16) & 1u);
  return (unsigned short)(r >> 16);
}
// packed f32x2 -> f16x2 (v_cvt_pkrtz_f16_f32); builtin returns __fp16 vec -> cast
__device__ __forceinline__ half4_ pk4(float a, float b, float c, float d) {
  half2_ lo = __builtin_bit_cast(half2_, __builtin_amdgcn_cvt_pkrtz(a, b));
  half2_ hi = __builtin_bit_cast(half2_, __builtin_amdgcn_cvt_pkrtz(c, d));
  return __builtin_bit_cast(half4_,
      (int2_){__builtin_bit_cast(int, lo), __builtin_bit_cast(int, hi)});
}
__device__ __forceinline__ half8_ cat44(half4_ a, half4_ b) {
  int2_ ia = __builtin_bit_cast(int2_, a), ib = __builtin_bit_cast(int2_, b);
  int4_ r = {ia[0], ia[1], ib[0], ib[1]};
  return __builtin_bit_cast(half8_, r);
}

// async global->LDS, 16B per lane, dest = ldsbase + lane*16 (wave-uniform base)
#define GLD16(gp, lp)                                                        \
  __builtin_amdgcn_global_load_lds(                                          \
      (const __attribute__((address_space(1))) unsigned int*)(gp),           \
      (__attribute__((address_space(3))) unsigned int*)(lp), 16, 0, 0)

#define VMCNT(n) asm volatile("s_waitcnt vmcnt(" #n ")" ::: "memory")
#define SCHED0   __builtin_amdgcn_sched_barrier(0)
#define SBAR     __builtin_amdgcn_s_barrier()

// ---------------------------------------------------------------------------
// Block-local dtype probe (verified R12): header x[0..255], exp-field>=134.
// ---------------------------------------------------------------------------
__device__ __forceinline__ bool detect_fp32_local(
    const unsigned short* __restrict__ xhdr, int* cnt_sh) {
  if (threadIdx.x == 0) *cnt_sh = 0;
  __syncthreads();
  unsigned int e = (xhdr[threadIdx.x] >> 7) & 0xFFu;
  if (e >= 134u) atomicAdd(cnt_sh, 1);
  __syncthreads();
  return *cnt_sh > 16;
}

// ---------------------------------------------------------------------------
// prep_all (verified R12): x convert + both weight transposes + Wband.
// ---------------------------------------------------------------------------
__device__ __forceinline__ void transpose_conv(
    const void* __restrict__ src, unsigned short* __restrict__ dst,
    int R, int C, int bx, int by, bool ofp) {
  __shared__ unsigned short tile[32][33];
  const int c0 = bx * 32, r0 = by * 32;
  const int tx = threadIdx.x & 31, ty = threadIdx.x >> 5;
#pragma unroll
  for (int k = 0; k < 4; ++k) {
    int r = ty + k * 8;
    long idx = (long)(r0 + r) * C + c0 + tx;
    tile[r][tx] = ofp ? f2b(((const float*)src)[idx])
                      : ((const unsigned short*)src)[idx];
  }
  __syncthreads();
#pragma unroll
  for (int k = 0; k < 4; ++k) {
    int c = ty + k * 8;
    dst[(long)(c0 + c) * R + r0 + tx] = tile[tx][c];
  }
}

__global__ __launch_bounds__(256) void prep_all(
    const void* __restrict__ xraw, const void* __restrict__ Wqraw,
    const void* __restrict__ Woraw, unsigned short* __restrict__ xb,
    unsigned short* __restrict__ WqT, unsigned short* __restrict__ WoT,
    unsigned short* __restrict__ Wband) {
  __shared__ int cnt_sh;
  const bool ofp = detect_fp32_local((const unsigned short*)xraw, &cnt_sh);
  const int bid = blockIdx.x;
  if (bid < 4096) {                       // x convert: 1048576 ushort4 units
    int i4 = bid * 256 + threadIdx.x;
    ushort4_ o;
    if (ofp) {
      float4_ v = ((const float4_*)xraw)[i4];
      o[0] = f2b(v[0]); o[1] = f2b(v[1]); o[2] = f2b(v[2]); o[3] = f2b(v[3]);
    } else {
      o = ((const ushort4_*)xraw)[i4];
    }
    *(ushort4_*)(xb + (long)i4 * 4) = o;
  } else if (bid < 5120) {
    const int b2 = bid - 4096;
    transpose_conv(Wqraw, WqT, 512, 2048, b2 % 64, b2 / 64, ofp);
  } else if (bid < 5632) {
    const int b2 = bid - 5120;
    transpose_conv(Woraw, WoT, 1024, 512, b2 % 16, b2 / 16, ofp);
  } else {
    constexpr float INV_E = 0.36787944117144233f;
    constexpr float R1 = 0.69220062755534635f;
    constexpr float INV_1MR = 3.2488706f;
    const int i = bid - 5632;
    const int krel = threadIdx.x;
    const int j = (i >> 6) * 64 - 96 + krel;
    float c = 0.f;
    if (j >= 0 && j < N_) {
      float wgt = __expf(-fabsf((float)(i - j)) * INV_E);
      float rj = __expf(-(float)j * INV_E);
      float rnj = __expf(-(float)(N_ - 1 - j) * INV_E);
      float S = 1.f + R1 * (2.f - rj - rnj) * INV_1MR;
      c = wgt / S;
    }
    _Float16 hv = (_Float16)c;
    Wband[i * 256 + krel] = __builtin_bit_cast(unsigned short, hv);
  }
}

// ---------------------------------------------------------------------------
// 256x256 8-phase GEMM (verified R1-R4; R5 showed it beats the 128-tile
// variant by ~5 us — 256 blocks / 1 per CU is FINE at this tile size).
// qkvt = xb @ WqT^T.  512 threads = 8 waves (2M x 4N), BK=64.
// ---------------------------------------------------------------------------
#define MFMA16x32(d, a, b) \
  d = __builtin_amdgcn_mfma_f32_16x16x32_bf16(a, b, d, 0, 0, 0)

__global__ __launch_bounds__(512, 2) void gemm256(
    const unsigned short* __restrict__ A, const unsigned short* __restrict__ Bt,
    unsigned short* __restrict__ C, int M, int N, int K) {
  __shared__ unsigned short As[2][16384];   // [buf][256 rows][64 k] bf16, 64 KB
  __shared__ unsigned short Bs[2][16384];   // [buf][256 n-rows][64 k]   64 KB
  const int tid = threadIdx.x;
  const int w = tid >> 6, lane = tid & 63, l16 = lane & 15, quad = lane >> 4;
  const int wm = w >> 2, wn = w & 3;        // wave grid 2M x 4N
  const long tm = (long)blockIdx.x * 256, tn = (long)blockIdx.y * 256;

  const int srow = tid >> 3;
  const int sch = (tid & 7) ^ (srow & 7);
  const unsigned short* gA = A + (tm + srow) * (long)K + sch * 8;
  const unsigned short* gB = Bt + (tn + srow) * (long)K + sch * 8;

  const int xr8 = l16 & 7;
  const int ch0 = ((0 + quad) ^ xr8) * 8;   // ks=0 chunk
  const int ch1 = ((4 + quad) ^ xr8) * 8;   // ks=1 chunk
  const int rowA0 = (wm * 128 + l16) * 64;
  const int rowB0 = (wn * 64 + l16) * 64;

  float4_ acc[8][4] = {};

  auto stage = [&](int t, int bufn) __attribute__((always_inline)) {
#pragma unroll
    for (int r = 0; r < 4; ++r)
      GLD16(gA + (long)(r * 64) * K + t * 64, &As[bufn][r * 4096 + w * 512]);
#pragma unroll
    for (int r = 0; r < 4; ++r)
      GLD16(gB + (long)(r * 64) * K + t * 64, &Bs[bufn][r * 4096 + w * 512]);
  };

  stage(0, 0);
  asm volatile("s_waitcnt vmcnt(0)" ::: "memory");
  __builtin_amdgcn_s_barrier();

  const int NT = K >> 6;                    // 8 K-tiles of 64
  for (int t = 0; t < NT; ++t) {
    const int buf = t & 1;
    const unsigned short* as = As[buf];
    const unsigned short* bs = Bs[buf];
    bf16x8 af[8], bq[4], br[4];
    // ---- q0: A-frags m0-3 + B-frags n0-1; issue next tile's stage ----
#pragma unroll
    for (int mi = 0; mi < 4; ++mi) {
      af[mi * 2]     = __builtin_bit_cast(bf16x8, *(const int4_*)&as[rowA0 + mi * 1024 + ch0]);
      af[mi * 2 + 1] = __builtin_bit_cast(bf16x8, *(const int4_*)&as[rowA0 + mi * 1024 + ch1]);
    }
#pragma unroll
    for (int ni = 0; ni < 2; ++ni) {
      bq[ni * 2]     = __builtin_bit_cast(bf16x8, *(const int4_*)&bs[rowB0 + ni * 1024 + ch0]);
      bq[ni * 2 + 1] = __builtin_bit_cast(bf16x8, *(const int4_*)&bs[rowB0 + ni * 1024 + ch1]);
    }
    if (t + 1 < NT) stage(t + 1, buf ^ 1);
    __builtin_amdgcn_s_barrier();
    asm volatile("s_waitcnt lgkmcnt(0)" ::: "memory");
    __builtin_amdgcn_sched_barrier(0);
    __builtin_amdgcn_s_setprio(1);
#pragma unroll
    for (int mi = 0; mi < 4; ++mi)
#pragma unroll
      for (int ni = 0; ni < 2; ++ni) {
        MFMA16x32(acc[mi][ni], af[mi * 2], bq[ni * 2]);
        MFMA16x32(acc[mi][ni], af[mi * 2 + 1], bq[ni * 2 + 1]);
      }
    __builtin_amdgcn_s_setprio(0);
    __builtin_amdgcn_s_barrier();
    // ---- q1: B-frags n2-3 (A m0-3 reused) ----
#pragma unroll
    for (int ni = 0; ni < 2; ++ni) {
      br[ni * 2]     = __builtin_bit_cast(bf16x8, *(const int4_*)&bs[rowB0 + (2 + ni) * 1024 + ch0]);
      br[ni * 2 + 1] = __builtin_bit_cast(bf16x8, *(const int4_*)&bs[rowB0 + (2 + ni) * 1024 + ch1]);
    }
    __builtin_amdgcn_s_barrier();
    asm volatile("s_waitcnt lgkmcnt(0)" ::: "memory");
    __builtin_amdgcn_sched_barrier(0);
    __builtin_amdgcn_s_setprio(1);
#pragma unroll
    for (int mi = 0; mi < 4; ++mi)
#pragma unroll
      for (int ni = 0; ni < 2; ++ni) {
        MFMA16x32(acc[mi][2 + ni], af[mi * 2], br[ni * 2]);
        MFMA16x32(acc[mi][2 + ni], af[mi * 2 + 1], br[ni * 2 + 1]);
      }
    __builtin_amdgcn_s_setprio(0);
    __builtin_amdgcn_s_barrier();
    // ---- q2: A-frags m4-7 (B n2-3 reused) ----
#pragma unroll
    for (int mi = 0; mi < 4; ++mi) {
      af[mi * 2]     = __builtin_bit_cast(bf16x8, *(const int4_*)&as[rowA0 + (4 + mi) * 1024 + ch0]);
      af[mi * 2 + 1] = __builtin_bit_cast(bf16x8, *(const int4_*)&as[rowA0 + (4 + mi) * 1024 + ch1]);
    }
    __builtin_amdgcn_s_barrier();
    asm volatile("s_waitcnt lgkmcnt(0)" ::: "memory");
    __builtin_amdgcn_sched_barrier(0);
    __builtin_amdgcn_s_setprio(1);
#pragma unroll
    for (int mi = 0; mi < 4; ++mi)
#pragma unroll
      for (int ni = 0; ni < 2; ++ni) {
        MFMA16x32(acc[4 + mi][2 + ni], af[mi * 2], br[ni * 2]);
        MFMA16x32(acc[4 + mi][2 + ni], af[mi * 2 + 1], br[ni * 2 + 1]);
      }
    __builtin_amdgcn_s_setprio(0);
    __builtin_amdgcn_s_barrier();
    // ---- q3: B-frags n0-1 again; end-of-tile vmcnt drain ----
#pragma unroll
    for (int ni = 0; ni < 2; ++ni) {
      bq[ni * 2]     = __builtin_bit_cast(bf16x8, *(const int4_*)&bs[rowB0 + ni * 1024 + ch0]);
      bq[ni * 2 + 1] = __builtin_bit_cast(bf16x8, *(const int4_*)&bs[rowB0 + ni * 1024 + ch1]);
    }
    __builtin_amdgcn_s_barrier();
    asm volatile("s_waitcnt lgkmcnt(0)" ::: "memory");
    __builtin_amdgcn_sched_barrier(0);
    __builtin_amdgcn_s_setprio(1);
#pragma unroll
    for (int mi = 0; mi < 4; ++mi)
#pragma unroll
      for (int ni = 0; ni < 2; ++ni) {
        MFMA16x32(acc[4 + mi][ni], af[mi * 2], bq[ni * 2]);
        MFMA16x32(acc[4 + mi][ni], af[mi * 2 + 1], bq[ni * 2 + 1]);
      }
    __builtin_amdgcn_s_setprio(0);
    asm volatile("s_waitcnt vmcnt(0)" ::: "memory");
    __builtin_amdgcn_sched_barrier(0);
    __builtin_amdgcn_s_barrier();
  }
#pragma unroll
  for (int ni = 0; ni < 4; ++ni) {
    long col = tn + wn * 64 + ni * 16 + l16;
#pragma unroll
    for (int mi = 0; mi < 8; ++mi)
#pragma unroll
      for (int r = 0; r < 4; ++r) {
        long row = tm + wm * 128 + mi * 16 + quad * 4 + r;
        C[row * N + col] = f2b(acc[mi][ni][r]);
      }
  }
}

// ---------------------------------------------------------------------------
// gemm_o (verified R4): output GEMM d_out = catb @ WoT^T + bias, 128x128 /
// BK=64, 8 waves, grid 64x4 = 256 blocks.
// ---------------------------------------------------------------------------
__global__ __launch_bounds__(512, 2) void gemm_o(
    const unsigned short* __restrict__ A, const unsigned short* __restrict__ Bt,
    void* __restrict__ C, const void* __restrict__ bias_raw,
    const unsigned short* __restrict__ xhdr) {
  __shared__ int cnt_sh;
  const bool ofp = detect_fp32_local(xhdr, &cnt_sh);
  __shared__ unsigned short As[2][8192];    // [buf][128 rows][64 k], 16 KB plane
  __shared__ unsigned short Bs[2][8192];
  constexpr int K = 1024, N = 512;
  const int tid = threadIdx.x;
  const int w = tid >> 6, lane = tid & 63, l16 = lane & 15, quad = lane >> 4;
  const int wm = w >> 2, wn = w & 3;        // 2M x 4N
  const long tm = (long)blockIdx.x * 128, tn = (long)blockIdx.y * 128;
  const int srow = tid >> 3;                // 0..63
  const int sch = (tid & 7) ^ (srow & 7);
  const unsigned short* gA = A + (tm + srow) * (long)K + sch * 8;
  const unsigned short* gB = Bt + (tn + srow) * (long)K + sch * 8;
  const int xr8 = l16 & 7;
  const int ch0 = ((0 + quad) ^ xr8) * 8;
  const int ch1 = ((4 + quad) ^ xr8) * 8;
  const int rowA0 = (wm * 64 + l16) * 64;
  const int rowB0 = (wn * 32 + l16) * 64;
  float4_ acc[4][2] = {};

  auto stage = [&](int t, int bufn) __attribute__((always_inline)) {
#pragma unroll
    for (int r = 0; r < 2; ++r)
      GLD16(gA + (long)(r * 64) * K + t * 64, &As[bufn][r * 4096 + w * 512]);
#pragma unroll
    for (int r = 0; r < 2; ++r)
      GLD16(gB + (long)(r * 64) * K + t * 64, &Bs[bufn][r * 4096 + w * 512]);
  };

  stage(0, 0);
  asm volatile("s_waitcnt vmcnt(0)" ::: "memory");
  __builtin_amdgcn_s_barrier();

  const int NT = K >> 6;                    // 16 K-tiles
  for (int t = 0; t < NT; ++t) {
    const int buf = t & 1;
    const unsigned short* as = As[buf];
    const unsigned short* bs = Bs[buf];
    bf16x8 af[8], bf0[2], bf1[2];
#pragma unroll
    for (int mi = 0; mi < 4; ++mi) {
      af[mi * 2]     = __builtin_bit_cast(bf16x8, *(const int4_*)&as[rowA0 + mi * 1024 + ch0]);
      af[mi * 2 + 1] = __builtin_bit_cast(bf16x8, *(const int4_*)&as[rowA0 + mi * 1024 + ch1]);
    }
    bf0[0] = __builtin_bit_cast(bf16x8, *(const int4_*)&bs[rowB0 + ch0]);
    bf0[1] = __builtin_bit_cast(bf16x8, *(const int4_*)&bs[rowB0 + ch1]);
    if (t + 1 < NT) stage(t + 1, buf ^ 1);
    __builtin_amdgcn_s_barrier();
    asm volatile("s_waitcnt lgkmcnt(0)" ::: "memory");
    __builtin_amdgcn_sched_barrier(0);
    __builtin_amdgcn_s_setprio(1);
#pragma unroll
    for (int mi = 0; mi < 4; ++mi) {
      MFMA16x32(acc[mi][0], af[mi * 2], bf0[0]);
      MFMA16x32(acc[mi][0], af[mi * 2 + 1], bf0[1]);
    }
    __builtin_amdgcn_s_setprio(0);
    __builtin_amdgcn_s_barrier();
    bf1[0] = __builtin_bit_cast(bf16x8, *(const int4_*)&bs[rowB0 + 1024 + ch0]);
    bf1[1] = __builtin_bit_cast(bf16x8, *(const int4_*)&bs[rowB0 + 1024 + ch1]);
    __builtin_amdgcn_s_barrier();
    asm volatile("s_waitcnt lgkmcnt(0)" ::: "memory");
    __builtin_amdgcn_sched_barrier(0);
    __builtin_amdgcn_s_setprio(1);
#pragma unroll
    for (int mi = 0; mi < 4; ++mi) {
      MFMA16x32(acc[mi][1], af[mi * 2], bf1[0]);
      MFMA16x32(acc[mi][1], af[mi * 2 + 1], bf1[1]);
    }
    __builtin_amdgcn_s_setprio(0);
    asm volatile("s_waitcnt vmcnt(0)" ::: "memory");
    __builtin_amdgcn_sched_barrier(0);
    __builtin_amdgcn_s_barrier();
  }
#pragma unroll
  for (int nb = 0; nb < 2; ++nb) {
    long col = tn + wn * 32 + nb * 16 + l16;
    float bv = ofp ? ((const float*)bias_raw)[col]
                   : b2f(((const unsigned short*)bias_raw)[col]);
#pragma unroll
    for (int mb = 0; mb < 4; ++mb)
#pragma unroll
      for (int r = 0; r < 4; ++r) {
        long row = tm + wm * 64 + mb * 16 + quad * 4 + r;
        float val = acc[mb][nb][r] + bv;
        if (ofp) ((float*)C)[row * N + col] = val;
        else ((unsigned short*)C)[row * N + col] = f2b(val);
      }
  }
}

// ---------------------------------------------------------------------------
// mid_all v2 (verified R2) — vectorized 16B/lane global I/O on both paths.
// ---------------------------------------------------------------------------
#define TSW 266
__global__ __launch_bounds__(256) void mid_all(
    const unsigned short* __restrict__ qkvt, unsigned short* __restrict__ Vt,
    const unsigned short* __restrict__ Wband, unsigned short* __restrict__ catb) {
  __shared__ __align__(16) unsigned short Ts[64 * TSW];  // 34 KB, aliased below
  const int bid = blockIdx.x;
  const int tid = threadIdx.x;
  if (bid < 512) {
    // ---- Vt tile: bh = bid>>4, j0 = (bid&15)*128 ----
    unsigned int* Td = (unsigned int*)Ts;           // [64 d][68 dwords]
    const int bh = bid >> 4, b = bh >> 3, h = bh & 7;
    const int j0 = (bid & 15) * 128;
    const int dg = tid & 7;
#pragma unroll
    for (int it = 0; it < 2; ++it) {
      const int jp = (tid >> 3) + 32 * it;          // j-pair index 0..63
      const long base =
          (long)(b * N_ + j0 + 2 * jp) * 2048 + 1024 + h * 64 + dg * 8;
      ushort8_ r0 = __builtin_bit_cast(ushort8_, *(const int4_*)&qkvt[base]);
      ushort8_ r1 = __builtin_bit_cast(ushort8_, *(const int4_*)&qkvt[base + 2048]);
#pragma unroll
      for (int e = 0; e < 8; ++e) {
        const int d = dg * 8 + e;
        const int S = (d >> 3) | ((d & 1) << 3);
        unsigned short h0 = __builtin_bit_cast(unsigned short, (_Float16)b2f(r0[e]));
        unsigned short h1 = __builtin_bit_cast(unsigned short, (_Float16)b2f(r1[e]));
        Td[d * 68 + (jp ^ (S << 2))] = (unsigned int)h0 | ((unsigned int)h1 << 16);
      }
    }
    __syncthreads();
#pragma unroll
    for (int it = 0; it < 4; ++it) {
      const int d = (tid >> 4) + 16 * it;           // 0..63
      const int ch = tid & 15;                      // logical 4-dword chunk
      const int S = (d >> 3) | ((d & 1) << 3);
      int4_ v = *(const int4_*)&Td[d * 68 + ((ch ^ S) << 2)];
      *(int4_*)&Vt[((long)bh * 64 + d) * 2048 + j0 + ch * 8] = v;
    }
    return;
  }
  // ---- branch2, self-staged (vectorized) ----
  const int b2 = bid - 512;
  const int qtile = b2 & 31;
  const int bh = b2 >> 5, b = bh >> 3, h = bh & 7;
  const int jlo = qtile * 64 - 96;
  {
    unsigned int* Tsd = (unsigned int*)Ts;          // dword view, row stride 133
    const int dg = tid & 7;
#pragma unroll
    for (int it = 0; it < 4; ++it) {
      const int kkp = (tid >> 3) + 32 * it;         // kk-pair 0..127
      const int jA = jlo + 2 * kkp, jB = jA + 1;
      int4_ r0 = {}, r1 = {};
      if (jA >= 0 && jA < N_)
        r0 = *(const int4_*)&qkvt[(long)(b * N_ + jA) * 2048 + 1536 + h * 64 + dg * 8];
      if (jB >= 0 && jB < N_)
        r1 = *(const int4_*)&qkvt[(long)(b * N_ + jB) * 2048 + 1536 + h * 64 + dg * 8];
      ushort8_ u0 = __builtin_bit_cast(ushort8_, r0);
      ushort8_ u1 = __builtin_bit_cast(ushort8_, r1);
#pragma unroll
      for (int e = 0; e < 8; ++e) {
        const int d = dg * 8 + e;
        unsigned short h0 = __builtin_bit_cast(unsigned short, (_Float16)b2f(u0[e]));
        unsigned short h1 = __builtin_bit_cast(unsigned short, (_Float16)b2f(u1[e]));
        Tsd[d * 133 + kkp] = (unsigned int)h0 | ((unsigned int)h1 << 16);
      }
    }
  }
  __syncthreads();
  const int w = tid >> 6, lane = tid & 63, l16 = lane & 15, quad = lane >> 4;
  const int i_row = qtile * 64 + w * 16 + l16;
  const unsigned short* ap = Wband + i_row * 256;
  float4_ acc[4] = {};
#pragma unroll
  for (int kh = 0; kh < 8; ++kh) {
    half8_ af = __builtin_bit_cast(half8_, *(const int4_*)&ap[kh * 32 + quad * 8]);
#pragma unroll
    for (int nb = 0; nb < 4; ++nb) {
      half8_ bf = __builtin_bit_cast(half8_,
          *(const int4_*)&Ts[(nb * 16 + l16) * TSW + kh * 32 + quad * 8]);
      acc[nb] = __builtin_amdgcn_mfma_f32_16x16x32_f16(af, bf, acc[nb], 0, 0, 0);
    }
  }
#pragma unroll
  for (int nb = 0; nb < 4; ++nb)
#pragma unroll
    for (int r = 0; r < 4; ++r) {
      int row = qtile * 64 + w * 16 + quad * 4 + r;
      catb[(long)(b * N_ + row) * 1024 + h * 128 + 64 + nb * 16 + l16] =
          f2b(acc[nb][r]);
    }
}

// ---------------------------------------------------------------------------
// Flash attention v13 = v12 + T3/T4 counted-vmcnt pipeline (4-buffer LDS,
// prefetch distance 2).  R7 analysis: phase = 4080 cyc vs ~700 cyc of work;
// __syncthreads() drains vmcnt(0) on loads issued ONE phase body earlier ->
// phase time pinned by 64-lane-scatter load latency.  Now: stage K(i+2) and
// V(i+1) during phase i; raw s_barrier with vmcnt(4) (this phase's 4 loads
// stay in flight; previous phase's loads — exactly the ones needed after the
// barrier — are confirmed complete).  Never drains to 0 in the main loop.
// ---------------------------------------------------------------------------
__global__ __launch_bounds__(256) void flash_kernel(
    const unsigned short* __restrict__ qkvt, const unsigned short* __restrict__ Vt,
    unsigned short* __restrict__ catb) {
  __shared__ unsigned short Ks[4][64 * 64];  // [buf][key][dim] bf16, swizzled
  __shared__ unsigned short Vs[4][64 * 64];  // [buf][d][key] f16, swizzled
  const int flat = blockIdx.x + blockIdx.y * 16;   // 512 blocks
  const int slot = flat & 7, idx = flat >> 3;      // slot = XCD (round-robin)
  const int bh = slot * 4 + (idx >> 4);            // 4 (b,h) groups per XCD
  const int i0 = (idx & 15) * 128;
  const int b = bh >> 3, h = bh & 7;
  const int tid = threadIdx.x;
  const int w = tid >> 6, lane = tid & 63, l16 = lane & 15, quad = lane >> 4;
  const int srow8 = lane >> 3, sch = lane & 7;
  const int chK = sch ^ srow8;
  bf16x8 qf[2][2];                            // [qset][kh]
  {
    constexpr float SCL = 0.125f * 1.44269504088896f;
#pragma unroll
    for (int s2 = 0; s2 < 2; ++s2) {
      const long qrow =
          (long)(b * N_ + i0 + w * 32 + s2 * 16 + l16) * 2048 + h * 64;
#pragma unroll
      for (int kh = 0; kh < 2; ++kh) {
        ushort8_ raw = __builtin_bit_cast(ushort8_,
            *(const int4_*)&qkvt[qrow + kh * 32 + quad * 8]);
        ushort8_ sc;
#pragma unroll
        for (int e = 0; e < 8; ++e) sc[e] = f2b(b2f(raw[e]) * SCL);
        qf[s2][kh] = __builtin_bit_cast(bf16x8, sc);
      }
    }
  }
  const unsigned short* kp[2];
#pragma unroll
  for (int kh = 0; kh < 2; ++kh)
    kp[kh] = &Ks[0][l16 * 64 + (((kh * 4 + quad) ^ (l16 & 7)) * 8)];
  // K=32 PV: window wd reads 16B = keys wd*32 + quad*8 .. +7 at d-row l16
  const unsigned short* vp32[2];
#pragma unroll
  for (int wd = 0; wd < 2; ++wd)
    vp32[wd] = &Vs[0][l16 * 64 + (((wd * 4 + quad) ^ (l16 & 7)) * 8)];
  const unsigned short* kg[2];
  const unsigned short* vg[2];
#pragma unroll
  for (int g = 0; g < 2; ++g) {
    const int prow = w * 16 + g * 8 + srow8;   // LDS row this thread stages
    // token permutation: LDS row p holds token T(p) so QK D-frag lands in
    // K=32 A-layout.  T = {p5, p3, p2, p4, p1, p0} (bijective bit shuffle).
    const int ptok = (prow & 0x20) | ((prow & 0x10) >> 2) |
                     ((prow & 0x0C) << 1) | (prow & 3);
    kg[g] = qkvt + (long)(b * N_ + ptok) * 2048 + 512 + h * 64 + chK * 8;
    vg[g] = Vt + ((long)bh * 64 + prow) * 2048 + chK * 8;   // V unpermuted
  }
  float4_ O[2][4] = {};
  float4_ O5[2] = {};
  const half8_ ones8 = {(_Float16)1.f, (_Float16)1.f, (_Float16)1.f, (_Float16)1.f,
                        (_Float16)1.f, (_Float16)1.f, (_Float16)1.f, (_Float16)1.f};

  auto stage_k = [&](int jt_, int buf_) __attribute__((always_inline)) {
    const int j0 = jt_ * 64;
#pragma unroll
    for (int g = 0; g < 2; ++g)
      GLD16(kg[g] + (long)j0 * 2048,
            (char*)&Ks[0][0] + buf_ * 8192 + (w * 16 + g * 8) * 128);
  };
  auto stage_v = [&](int jt_, int buf_) __attribute__((always_inline)) {
    const int j0 = jt_ * 64;
#pragma unroll
    for (int g = 0; g < 2; ++g)
      GLD16(vg[g] + j0,
            (char*)&Vs[0][0] + buf_ * 8192 + (w * 16 + g * 8) * 128);
  };
  // one PV accumulation step from pf (prev phase's P) against Vs buffer vb
  auto pv_step = [&](half4_ (&pf)[2][4], int vb) __attribute__((always_inline)) {
#pragma unroll
    for (int wd = 0; wd < 2; ++wd) {
      half8_ pa0 = cat44(pf[0][2 * wd], pf[0][2 * wd + 1]);
      half8_ pa1 = cat44(pf[1][2 * wd], pf[1][2 * wd + 1]);
#pragma unroll
      for (int dblk = 0; dblk < 4; ++dblk) {
        half8_ vfv = *(const half8_*)(vp32[wd] + vb + dblk * 1024);
        O[0][dblk] = __builtin_amdgcn_mfma_f32_16x16x32_f16(
            pa0, vfv, O[0][dblk], 0, 0, 0);
        O[1][dblk] = __builtin_amdgcn_mfma_f32_16x16x32_f16(
            pa1, vfv, O[1][dblk], 0, 0, 0);
      }
      O5[0] = __builtin_amdgcn_mfma_f32_16x16x32_f16(pa0, ones8, O5[0], 0, 0, 0);
      O5[1] = __builtin_amdgcn_mfma_f32_16x16x32_f16(pa1, ones8, O5[1], 0, 0, 0);
    }
  };
  // phase body i: [issue K(i+2), V(i+1) per flags]; QK(i); PV(i-1); exp(i).
  // Caller appends the counted vmcnt + barrier.
  auto phase_body = [&](int i, half4_ (&pfp)[2][4], half4_ (&pfc)[2][4],
                        bool first, bool stK, bool stV)
      __attribute__((always_inline)) {
    if (stK) stage_k(i + 2, (i + 2) & 3);
    if (stV) stage_v(i + 1, (i + 1) & 3);
    const int kb = (i & 3) * 4096;
    float4_ s[2][4] = {};
#pragma unroll
    for (int kh = 0; kh < 2; ++kh)
#pragma unroll
      for (int c = 0; c < 4; ++c) {
        bf16x8 kf = __builtin_bit_cast(bf16x8,
            *(const int4_*)(kp[kh] + kb + c * 1024));
#pragma unroll
        for (int s2 = 0; s2 < 2; ++s2)
          s[s2][c] = __builtin_amdgcn_mfma_f32_16x16x32_bf16(
              kf, qf[s2][kh], s[s2][c], 0, 0, 0);
      }
    if (!first) pv_step(pfp, ((i - 1) & 3) * 4096);
#pragma unroll
    for (int s2 = 0; s2 < 2; ++s2)
#pragma unroll
      for (int c = 0; c < 4; ++c)
        pfc[s2][c] = pk4(EXP2(s[s2][c][0]), EXP2(s[s2][c][1]),
                         EXP2(s[s2][c][2]), EXP2(s[s2][c][3]));
  };

  half4_ pfA[2][4], pfB[2][4];
  // prologue: K(0),K(1),V(0) in flight; K(0) must be complete -> vmcnt(4)
  stage_k(0, 0);
  stage_k(1, 1);
  stage_v(0, 0);
  VMCNT(4); SCHED0; SBAR;
  // phase 0: issue K(2),V(1); QK(0); exp(0)->pfA.  vmcnt(4) -> K(1),V(0) done.
  phase_body(0, pfB, pfA, true, true, true);
  VMCNT(4); SCHED0; SBAR;
  for (int jt = 1; jt < 29; jt += 2) {
    phase_body(jt, pfA, pfB, false, true, true);
    VMCNT(4); SCHED0; SBAR;
    phase_body(jt + 1, pfB, pfA, false, true, true);
    VMCNT(4); SCHED0; SBAR;
  }
  // phase 29: issues K(31),V(30); vmcnt(4) -> K(30),V(29) done
  phase_body(29, pfA, pfB, false, true, true);
  VMCNT(4); SCHED0; SBAR;
  // phase 30: issues V(31) only (2 loads); vmcnt(2) -> K(31),V(30) done
  phase_body(30, pfB, pfA, false, false, true);
  VMCNT(2); SCHED0; SBAR;
  // phase 31: no issues; vmcnt(0) -> V(31) done for final pv_step
  phase_body(31, pfA, pfB, false, false, false);
  VMCNT(0); SCHED0; SBAR;
  pv_step(pfB, (31 & 3) * 4096);            // final PV(31)

#pragma unroll
  for (int s2 = 0; s2 < 2; ++s2) {
    float linv[4];
#pragma unroll
    for (int r = 0; r < 4; ++r) linv[r] = 1.f / O5[s2][r];
#pragma unroll
    for (int dblk = 0; dblk < 4; ++dblk)
#pragma unroll
      for (int r = 0; r < 4; ++r) {
        int row = i0 + w * 32 + s2 * 16 + quad * 4 + r;
        catb[(long)(b * N_ + row) * 1024 + h * 128 + dblk * 16 + l16] =
            f2b(O[s2][dblk][r] * linv[r]);
      }
  }
}

// ---------------------------------------------------------------------------
extern "C" void kernel_launch(void* const* d_in, const int* in_sizes, int n_in,
                              void* d_out, int out_size, void* d_ws, size_t ws_size,
                              hipStream_t stream) {
  char* ws = (char*)d_ws;
  unsigned short* qkvt = (unsigned short*)(ws);                            // 32 MB
  unsigned short* WqT  = (unsigned short*)(ws + (size_t)32 * 1024 * 1024); //  2 MB
  unsigned short* WoT  = (unsigned short*)(ws + (size_t)34 * 1024 * 1024); //  1 MB
  unsigned short* Vt   = (unsigned short*)(ws + (size_t)35 * 1024 * 1024); //  8 MB
  unsigned short* catb = (unsigned short*)(ws + (size_t)43 * 1024 * 1024); // 16 MB
  unsigned short* xb   = (unsigned short*)(ws + (size_t)59 * 1024 * 1024); //  8 MB
  unsigned short* Wband= (unsigned short*)(ws + (size_t)68 * 1024 * 1024); //  1 MB

  prep_all<<<7680, 256, 0, stream>>>(d_in[0], d_in[1], d_in[2],
                                     xb, WqT, WoT, Wband);
  gemm256<<<dim3(8192 / 256, 2048 / 256), 512, 0, stream>>>(
      xb, WqT, qkvt, 8192, 2048, 512);
  mid_all<<<1536, 256, 0, stream>>>(qkvt, Vt, Wband, catb);
  flash_kernel<<<dim3(2048 / 128, 32), 256, 0, stream>>>(qkvt, Vt, catb);
  gemm_o<<<dim3(8192 / 128, 512 / 128), 512, 0, stream>>>(
      catb, WoT, d_out, d_in[3], (const unsigned short*)d_in[0]);
}